// Round 11
// baseline (513.686 us; speedup 1.0000x reference)
//
#include <hip/hip_runtime.h>
#include <math.h>

// ---------------- types / helpers ----------------
typedef __attribute__((ext_vector_type(8))) short bf16x8;
typedef __attribute__((ext_vector_type(4))) short bf16x4;
typedef __attribute__((ext_vector_type(4))) float f32x4;

__device__ __forceinline__ unsigned short f2bf(float f) {
  unsigned u = __builtin_bit_cast(unsigned, f);
  u += 0x7fffu + ((u >> 16) & 1u);           // RNE
  return (unsigned short)(u >> 16);
}
__device__ __forceinline__ float bf2f(unsigned short h) {
  return __builtin_bit_cast(float, (unsigned)h << 16);
}

#define MFMA16(a, b, c) __builtin_amdgcn_mfma_f32_16x16x32_bf16((a), (b), (c), 0, 0, 0)

__device__ __forceinline__ void gload_lds16(const void* g, void* l) {
  __builtin_amdgcn_global_load_lds(
      (const __attribute__((address_space(1))) unsigned*)g,
      (__attribute__((address_space(3))) unsigned*)l, 16, 0, 0);
}

// bijective XCD swizzle (m204)
__device__ __forceinline__ int xcd_swz(int bid, int nwg) {
  int q = nwg >> 3, r = nwg & 7;
  int xcd = bid & 7, off = bid >> 3;
  return (xcd < r ? xcd * (q + 1) : r * (q + 1) + (xcd - r) * q) + off;
}

// ---------------- fused fp32 -> bf16 convert (all 4 weights) ----------------
__global__ __launch_bounds__(256) void k_cvt4(
    const float* __restrict__ wq, const float* __restrict__ wp,
    const float* __restrict__ w1, const float* __restrict__ w2,
    unsigned short* __restrict__ oq, unsigned short* __restrict__ op,
    unsigned short* __restrict__ o1, unsigned short* __restrict__ o2) {
  int bid = blockIdx.x;
  const float* src; unsigned short* dst; int base;
  if (bid < 3072)      { src = wq; dst = oq; base = bid; }
  else if (bid < 4096) { src = wp; dst = op; base = bid - 3072; }
  else if (bid < 8192) { src = w1; dst = o1; base = bid - 4096; }
  else                 { src = w2; dst = o2; base = bid - 8192; }
  int i = base * 256 + threadIdx.x;
  float4 v = ((const float4*)src)[i];
  bf16x4 o;
  o[0] = (short)f2bf(v.x); o[1] = (short)f2bf(v.y);
  o[2] = (short)f2bf(v.z); o[3] = (short)f2bf(v.w);
  *(bf16x4*)(dst + (size_t)i * 4) = o;
}

// ---------------- layernorm (1024 cols, 1 block/row) -> bf16 ----------------
__global__ __launch_bounds__(256) void k_ln(const float* __restrict__ x,
                                            const float* __restrict__ g,
                                            const float* __restrict__ b,
                                            unsigned short* __restrict__ out) {
  __shared__ float red[8];
  const int tid = threadIdx.x;
  const size_t row = blockIdx.x;
  float4 v = ((const float4*)(x + row * 1024))[tid];
  float s = v.x + v.y + v.z + v.w;
#pragma unroll
  for (int off = 32; off; off >>= 1) s += __shfl_xor(s, off);
  if ((tid & 63) == 0) red[tid >> 6] = s;
  __syncthreads();
  float mu = (red[0] + red[1] + red[2] + red[3]) * (1.0f / 1024.0f);
  float dx = v.x - mu, dy = v.y - mu, dz = v.z - mu, dw = v.w - mu;
  float s2 = dx * dx + dy * dy + dz * dz + dw * dw;
#pragma unroll
  for (int off = 32; off; off >>= 1) s2 += __shfl_xor(s2, off);
  if ((tid & 63) == 0) red[4 + (tid >> 6)] = s2;
  __syncthreads();
  float var = (red[4] + red[5] + red[6] + red[7]) * (1.0f / 1024.0f);
  float rstd = rsqrtf(var + 1e-5f);
  float4 gv = ((const float4*)g)[tid];
  float4 bv = ((const float4*)b)[tid];
  bf16x4 o;
  o[0] = (short)f2bf(dx * rstd * gv.x + bv.x);
  o[1] = (short)f2bf(dy * rstd * gv.y + bv.y);
  o[2] = (short)f2bf(dz * rstd * gv.z + bv.z);
  o[3] = (short)f2bf(dw * rstd * gv.w + bv.w);
  *(bf16x4*)(out + row * 1024 + tid * 4) = o;
}

// ============ 256x256 multi-phase GEMM: C[M,N] = A[M,K] @ B[N,K]^T ============
// (unchanged — passed refcheck rounds 3-10)
template <int EPI>
__global__ __launch_bounds__(512, 2) void k_gemm256(
    const unsigned short* __restrict__ A, const unsigned short* __restrict__ Bw,
    int Ndim, int K, int nby,
    const float* __restrict__ bias,
    unsigned short* __restrict__ Qc, unsigned short* __restrict__ Kc,
    unsigned short* __restrict__ VTo,
    unsigned short* __restrict__ outb) {
  __shared__ __align__(16) unsigned short lds[2][2][16384];  // [buf][A|B][256*64]

  const int tid = threadIdx.x;
  const int wid = tid >> 6, lane = tid & 63;
  const int wm = wid >> 2, wn = wid & 3;
  const int lr = lane & 15, lhi = lane >> 4;

  const int nwg = gridDim.x;
  const int swz = xcd_swz(blockIdx.x, nwg);
  const int bcol = swz / nby, brow = swz % nby;

  const size_t a_base = (size_t)brow * 256 * K;
  const size_t b_base = (size_t)bcol * 256 * K;
  const int NT = K >> 6;

  auto STAGE = [&](int dbuf, int kt, int which) {
    int ktc = (kt < NT) ? kt : 0;
    int isB = which & 1;
    int odd = which >> 1;
    const unsigned short* src = isB ? (Bw + b_base) : (A + a_base);
    int col = (ktc << 6) + (((lane & 7) ^ ((lane >> 3) & 7)) << 3);
#pragma unroll
    for (int c = 0; c < 2; ++c) {
      int idx = (wid << 1) | c;
      int chunk = isB ? ((idx & 3) + ((idx >> 2) << 3) + (odd << 2))
                      : ((idx & 7) + ((idx >> 3) << 4) + (odd << 3));
      int row = (chunk << 3) + (lane >> 3);
      gload_lds16(src + (size_t)row * K + col,
                  &lds[dbuf][isB][chunk * 512 + lane * 8]);
    }
  };

  STAGE(0, 0, 0); STAGE(0, 0, 1); STAGE(0, 0, 2); STAGE(0, 0, 3);

  f32x4 acc[8][4] = {};
  bf16x8 aF0[4][2], aF1[4][2], bF0[2][2], bF1[2][2];

  const int colx0 = (lhi << 4) ^ ((lr & 7) << 4);
  const int colx1 = (64 + (lhi << 4)) ^ ((lr & 7) << 4);

  for (int t = 0; t < NT; ++t) {
    const int buf = t & 1;
    const char* sAb = (const char*)&lds[buf][0][0];
    const char* sBb = (const char*)&lds[buf][1][0];
#pragma unroll
    for (int q = 0; q < 4; ++q) {
      asm volatile("s_waitcnt vmcnt(6)" ::: "memory");
      __builtin_amdgcn_s_barrier();
      if (q == 0) {
#pragma unroll
        for (int m = 0; m < 4; ++m) {
          int ro = (wm * 128 + m * 16 + lr) * 128;
          aF0[m][0] = *(const bf16x8*)(sAb + ro + colx0);
          aF0[m][1] = *(const bf16x8*)(sAb + ro + colx1);
        }
      } else if (q == 1) {
#pragma unroll
        for (int n = 0; n < 2; ++n) {
          int ro = (wn * 64 + n * 16 + lr) * 128;
          bF0[n][0] = *(const bf16x8*)(sBb + ro + colx0);
          bF0[n][1] = *(const bf16x8*)(sBb + ro + colx1);
        }
      } else if (q == 2) {
#pragma unroll
        for (int m = 0; m < 4; ++m) {
          int ro = (wm * 128 + 64 + m * 16 + lr) * 128;
          aF1[m][0] = *(const bf16x8*)(sAb + ro + colx0);
          aF1[m][1] = *(const bf16x8*)(sAb + ro + colx1);
        }
      } else {
#pragma unroll
        for (int n = 0; n < 2; ++n) {
          int ro = (wn * 64 + 32 + n * 16 + lr) * 128;
          bF1[n][0] = *(const bf16x8*)(sBb + ro + colx0);
          bF1[n][1] = *(const bf16x8*)(sBb + ro + colx1);
        }
      }
      STAGE(buf ^ 1, t + 1, q);
      asm volatile("s_waitcnt lgkmcnt(0)" ::: "memory");
      __builtin_amdgcn_sched_barrier(0);
      __builtin_amdgcn_s_setprio(1);
      if (q == 0) {
        if (t > 0) {
#pragma unroll
          for (int m = 0; m < 4; ++m)
#pragma unroll
            for (int n = 0; n < 2; ++n)
#pragma unroll
              for (int kk = 0; kk < 2; ++kk)
                acc[4 + m][2 + n] = MFMA16(aF1[m][kk], bF1[n][kk], acc[4 + m][2 + n]);
        }
      } else if (q == 1) {
#pragma unroll
        for (int m = 0; m < 4; ++m)
#pragma unroll
          for (int n = 0; n < 2; ++n)
#pragma unroll
            for (int kk = 0; kk < 2; ++kk)
              acc[m][n] = MFMA16(aF0[m][kk], bF0[n][kk], acc[m][n]);
      } else if (q == 2) {
#pragma unroll
        for (int m = 0; m < 4; ++m)
#pragma unroll
          for (int n = 0; n < 2; ++n)
#pragma unroll
            for (int kk = 0; kk < 2; ++kk)
              acc[4 + m][n] = MFMA16(aF1[m][kk], bF0[n][kk], acc[4 + m][n]);
      } else {
#pragma unroll
        for (int m = 0; m < 4; ++m)
#pragma unroll
          for (int n = 0; n < 2; ++n)
#pragma unroll
            for (int kk = 0; kk < 2; ++kk)
              acc[m][2 + n] = MFMA16(aF0[m][kk], bF1[n][kk], acc[m][2 + n]);
      }
      __builtin_amdgcn_s_setprio(0);
    }
  }
#pragma unroll
  for (int m = 0; m < 4; ++m)
#pragma unroll
    for (int n = 0; n < 2; ++n)
#pragma unroll
      for (int kk = 0; kk < 2; ++kk)
        acc[4 + m][2 + n] = MFMA16(aF1[m][kk], bF1[n][kk], acc[4 + m][2 + n]);

  // ---- epilogue ----
  if (EPI == 0) {
    const int region = bcol >> 2;          // 0=Q, 1=K, 2=V (uniform)
    const int h = (bcol & 3) * 4 + wn;
    if (region < 2) {
      unsigned short* dst = (region == 0) ? Qc : Kc;  // [bh][kv][d]
#pragma unroll
      for (int m = 0; m < 8; ++m)
#pragma unroll
        for (int n = 0; n < 4; ++n) {
          int d = n * 16 + lr;
#pragma unroll
          for (int r = 0; r < 4; ++r) {
            int row = brow * 256 + wm * 128 + m * 16 + lhi * 4 + r;
            int b = row >> 10, kv = row & 1023;
            dst[((size_t)((b << 4) + h) << 16) + (size_t)kv * 64 + d] =
                f2bf(acc[m][n][r]);
          }
        }
    } else {
#pragma unroll
      for (int m = 0; m < 8; ++m)
#pragma unroll
        for (int n = 0; n < 4; ++n) {
          int d = n * 16 + lr;
          int row0_ = brow * 256 + wm * 128 + m * 16 + lhi * 4;
          int b = row0_ >> 10, kv0 = row0_ & 1023;
          bf16x4 o;
          o[0] = (short)f2bf(acc[m][n][0]);
          o[1] = (short)f2bf(acc[m][n][1]);
          o[2] = (short)f2bf(acc[m][n][2]);
          o[3] = (short)f2bf(acc[m][n][3]);
          *(bf16x4*)&VTo[((size_t)((b << 4) + h) << 16) + ((size_t)d << 10) + kv0] = o;
        }
    }
  } else {
#pragma unroll
    for (int m = 0; m < 8; ++m)
#pragma unroll
      for (int n = 0; n < 4; ++n) {
        int col = bcol * 256 + wn * 64 + n * 16 + lr;
        float bi = bias[col];
#pragma unroll
        for (int r = 0; r < 4; ++r) {
          int row = brow * 256 + wm * 128 + m * 16 + lhi * 4 + r;
          float v = acc[m][n][r] + bi;
          v = 0.5f * v * (1.0f + erff(v * 0.70710678118654752f));
          outb[(size_t)row * Ndim + col] = f2bf(v);
        }
      }
  }
}

// ======== 128x128 PIPELINED GEMM (4-phase counted-vmcnt) — unchanged R9 ========
__global__ __launch_bounds__(256) void k_gemm128p(
    const unsigned short* __restrict__ A, const unsigned short* __restrict__ Bw,
    int Ndim, int K, int nby,
    const float* __restrict__ bias, const float* __restrict__ gamma,
    const float* __restrict__ resid, float* __restrict__ outf) {
  __shared__ __align__(16) unsigned short lds[2][2][8192];  // [buf][A|B][128*64]

  const int tid = threadIdx.x;
  const int wid = tid >> 6, lane = tid & 63;
  const int wm = wid >> 1, wn = wid & 1;
  const int lr = lane & 15, lhi = lane >> 4;

  const int swz = xcd_swz(blockIdx.x, gridDim.x);
  const int bcol = swz / nby, brow = swz % nby;

  const size_t a_base = (size_t)brow * 128 * K;
  const size_t b_base = (size_t)bcol * 128 * K;
  const int NT = K >> 6;

  auto STAGE = [&](int dbuf, int kt, int which) {
    int ktc = (kt < NT) ? kt : 0;
    int isB = which & 1;
    int odd = which >> 1;
    const unsigned short* src = isB ? (Bw + b_base) : (A + a_base);
    int col = (ktc << 6) + (((lane & 7) ^ ((lane >> 3) & 7)) << 3);
#pragma unroll
    for (int c = 0; c < 2; ++c) {
      int idx = (wid << 1) | c;                            // 0..7
      int chunk = (idx & 3) + ((idx >> 2) << 3) + (odd << 2);
      int row = (chunk << 3) + (lane >> 3);
      gload_lds16(src + (size_t)row * K + col,
                  &lds[dbuf][isB][chunk * 512 + lane * 8]);
    }
  };

  STAGE(0, 0, 0); STAGE(0, 0, 1); STAGE(0, 0, 2); STAGE(0, 0, 3);

  f32x4 acc[4][4] = {};                   // [mh*2+m][nh*2+n]
  bf16x8 aF0[2][2], aF1[2][2], bF0[2][2], bF1[2][2];

  const int colx0 = (lhi << 4) ^ ((lr & 7) << 4);
  const int colx1 = (64 + (lhi << 4)) ^ ((lr & 7) << 4);

  for (int t = 0; t < NT; ++t) {
    const int buf = t & 1;
    const char* sAb = (const char*)&lds[buf][0][0];
    const char* sBb = (const char*)&lds[buf][1][0];
#pragma unroll
    for (int q = 0; q < 4; ++q) {
      asm volatile("s_waitcnt vmcnt(6)" ::: "memory");
      __builtin_amdgcn_s_barrier();
      if (q == 0) {
#pragma unroll
        for (int m = 0; m < 2; ++m) {
          int ro = (wm * 64 + m * 16 + lr) * 128;
          aF0[m][0] = *(const bf16x8*)(sAb + ro + colx0);
          aF0[m][1] = *(const bf16x8*)(sAb + ro + colx1);
        }
      } else if (q == 1) {
#pragma unroll
        for (int n = 0; n < 2; ++n) {
          int ro = (wn * 64 + n * 16 + lr) * 128;
          bF0[n][0] = *(const bf16x8*)(sBb + ro + colx0);
          bF0[n][1] = *(const bf16x8*)(sBb + ro + colx1);
        }
      } else if (q == 2) {
#pragma unroll
        for (int m = 0; m < 2; ++m) {
          int ro = (wm * 64 + 32 + m * 16 + lr) * 128;
          aF1[m][0] = *(const bf16x8*)(sAb + ro + colx0);
          aF1[m][1] = *(const bf16x8*)(sAb + ro + colx1);
        }
      } else {
#pragma unroll
        for (int n = 0; n < 2; ++n) {
          int ro = (wn * 64 + 32 + n * 16 + lr) * 128;
          bF1[n][0] = *(const bf16x8*)(sBb + ro + colx0);
          bF1[n][1] = *(const bf16x8*)(sBb + ro + colx1);
        }
      }
      STAGE(buf ^ 1, t + 1, q);
      asm volatile("s_waitcnt lgkmcnt(0)" ::: "memory");
      __builtin_amdgcn_sched_barrier(0);
      __builtin_amdgcn_s_setprio(1);
      if (q == 0) {
        if (t > 0) {
#pragma unroll
          for (int m = 0; m < 2; ++m)
#pragma unroll
            for (int n = 0; n < 2; ++n)
#pragma unroll
              for (int kk = 0; kk < 2; ++kk)
                acc[2 + m][2 + n] = MFMA16(aF1[m][kk], bF1[n][kk], acc[2 + m][2 + n]);
        }
      } else if (q == 1) {
#pragma unroll
        for (int m = 0; m < 2; ++m)
#pragma unroll
          for (int n = 0; n < 2; ++n)
#pragma unroll
            for (int kk = 0; kk < 2; ++kk)
              acc[m][n] = MFMA16(aF0[m][kk], bF0[n][kk], acc[m][n]);
      } else if (q == 2) {
#pragma unroll
        for (int m = 0; m < 2; ++m)
#pragma unroll
          for (int n = 0; n < 2; ++n)
#pragma unroll
            for (int kk = 0; kk < 2; ++kk)
              acc[2 + m][n] = MFMA16(aF1[m][kk], bF0[n][kk], acc[2 + m][n]);
      } else {
#pragma unroll
        for (int m = 0; m < 2; ++m)
#pragma unroll
          for (int n = 0; n < 2; ++n)
#pragma unroll
            for (int kk = 0; kk < 2; ++kk)
              acc[m][2 + n] = MFMA16(aF0[m][kk], bF1[n][kk], acc[m][2 + n]);
      }
      __builtin_amdgcn_s_setprio(0);
    }
  }
#pragma unroll
  for (int m = 0; m < 2; ++m)
#pragma unroll
    for (int n = 0; n < 2; ++n)
#pragma unroll
      for (int kk = 0; kk < 2; ++kk)
        acc[2 + m][2 + n] = MFMA16(aF1[m][kk], bF1[n][kk], acc[2 + m][2 + n]);

  // ---- epilogue: resid + (v + bias)*gamma -> f32 ----
#pragma unroll
  for (int i = 0; i < 4; ++i)
#pragma unroll
    for (int j = 0; j < 4; ++j) {
      int col = bcol * 128 + wn * 64 + (j >> 1) * 32 + (j & 1) * 16 + lr;
      float bi = bias[col], gm = gamma[col];
#pragma unroll
      for (int r = 0; r < 4; ++r) {
        int row = brow * 128 + wm * 64 + (i >> 1) * 32 + (i & 1) * 16 + lhi * 4 + r;
        outf[(size_t)row * Ndim + col] =
            resid[(size_t)row * Ndim + col] + (acc[i][j][r] + bi) * gm;
      }
    }
}

// ---------------- fused attention v7 (R9-exact, known good) ----------------
__global__ __launch_bounds__(256) void k_attn(const unsigned short* __restrict__ Qc,
                                              const unsigned short* __restrict__ Kc,
                                              const unsigned short* __restrict__ VT,
                                              float* __restrict__ attn_out,
                                              unsigned short* __restrict__ ao) {
  __shared__ __align__(16) char smem[16896];  // sP 4x4096; sAO overlays
  __shared__ float red[4][32][2];             // [wave][q-row][m,l]

  const int tid = threadIdx.x;
  const int wid = tid >> 6, lane = tid & 63;
  const int lr = lane & 15, lhi = lane >> 4;
  const int bid = blockIdx.x;
  const int bh = (bid & 7) + ((bid >> 8) << 3);   // XCD affinity: head -> one XCD
  const int q0 = ((bid >> 3) & 31) * 32;
  const int b = bh >> 4, h = bh & 15;
  const size_t hb = (size_t)bh << 16;  // per-head base (1024*64 elems)
  const int hcol = h * 64;

  bf16x8 af[2][2];
#pragma unroll
  for (int i = 0; i < 2; ++i)
#pragma unroll
    for (int kk = 0; kk < 2; ++kk)
      af[i][kk] = *(const bf16x8*)&Qc[hb + (size_t)(q0 + i * 16 + lr) * 64 +
                                      kk * 32 + lhi * 8];

  f32x4 acc[2][16] = {};
#pragma unroll
  for (int kk = 0; kk < 2; ++kk) {
#pragma unroll
    for (int j = 0; j < 16; ++j) {
      int m = wid * 256 + j * 16 + lr;
      bf16x8 bv = *(const bf16x8*)&Kc[hb + (size_t)m * 64 + kk * 32 + lhi * 8];
      acc[0][j] = MFMA16(af[0][kk], bv, acc[0][j]);
      acc[1][j] = MFMA16(af[1][kk], bv, acc[1][j]);
    }
  }

  float mw[2][4];
#pragma unroll
  for (int i = 0; i < 2; ++i)
#pragma unroll
    for (int r = 0; r < 4; ++r) {
      float m_ = -1e30f;
#pragma unroll
      for (int j = 0; j < 16; ++j) {
        acc[i][j][r] *= 0.125f;
        m_ = fmaxf(m_, acc[i][j][r]);
      }
#pragma unroll
      for (int off = 1; off < 16; off <<= 1) m_ = fmaxf(m_, __shfl_xor(m_, off));
      mw[i][r] = m_;
      float s_ = 0.f;
#pragma unroll
      for (int j = 0; j < 16; ++j) {
        float e = __expf(acc[i][j][r] - m_);
        acc[i][j][r] = e;
        s_ += e;
      }
#pragma unroll
      for (int off = 1; off < 16; off <<= 1) s_ += __shfl_xor(s_, off);
      if (lr == 0) {
        int rl = i * 16 + lhi * 4 + r;
        red[wid][rl][0] = m_;
        red[wid][rl][1] = s_;
      }
    }
  __syncthreads();

  float inv[2][4];
#pragma unroll
  for (int i = 0; i < 2; ++i)
#pragma unroll
    for (int r = 0; r < 4; ++r) {
      int rl = i * 16 + lhi * 4 + r;
      float m0 = red[0][rl][0], m1 = red[1][rl][0],
            m2 = red[2][rl][0], m3 = red[3][rl][0];
      float mg = fmaxf(fmaxf(m0, m1), fmaxf(m2, m3));
      float lg = red[0][rl][1] * __expf(m0 - mg) + red[1][rl][1] * __expf(m1 - mg) +
                 red[2][rl][1] * __expf(m2 - mg) + red[3][rl][1] * __expf(m3 - mg);
      inv[i][r] = __expf(mw[i][r] - mg) / lg;
    }

  unsigned pb[2][16][2];
#pragma unroll
  for (int i = 0; i < 2; ++i)
#pragma unroll
    for (int j = 0; j < 16; ++j) {
      pb[i][j][0] = (unsigned)f2bf(acc[i][j][0] * inv[i][0]) |
                    ((unsigned)f2bf(acc[i][j][1] * inv[i][1]) << 16);
      pb[i][j][1] = (unsigned)f2bf(acc[i][j][2] * inv[i][2]) |
                    ((unsigned)f2bf(acc[i][j][3] * inv[i][3]) << 16);
    }

  char* sP = smem + wid * 4096;
  f32x4 oaccT[4][2] = {};

#pragma unroll
  for (int t = 0; t < 4; ++t) {
#pragma unroll
    for (int i = 0; i < 2; ++i)
#pragma unroll
      for (int jl = 0; jl < 4; ++jl) {
        int j = t * 4 + jl;
        int kvl2 = (jl * 16 + lr) * 2;
#pragma unroll
        for (int hp = 0; hp < 2; ++hp) {
          unsigned d = pb[i][j][hp];
          int qa = i * 16 + lhi * 4 + hp * 2;
          int qb = qa + 1;
          *(unsigned short*)(sP + qa * 128 + (kvl2 ^ ((qa & 7) << 4))) =
              (unsigned short)(d & 0xffff);
          *(unsigned short*)(sP + qb * 128 + (kvl2 ^ ((qb & 7) << 4))) =
              (unsigned short)(d >> 16);
        }
      }
    {
      const float* ab = attn_out + (size_t)bh * 1048576 + (size_t)q0 * 1024 +
                        wid * 256 + t * 64;
#pragma unroll
      for (int s = 0; s < 8; ++s) {
        int row_l = s * 4 + (lane >> 4);
        int kvb = (lane & 15) * 8;
        bf16x4 p = *(const bf16x4*)(sP + row_l * 128 + (kvb ^ ((row_l & 7) << 4)));
        float4 o;
        o.x = bf2f((unsigned short)p[0]);
        o.y = bf2f((unsigned short)p[1]);
        o.z = bf2f((unsigned short)p[2]);
        o.w = bf2f((unsigned short)p[3]);
        *(float4*)((float*)ab + (size_t)row_l * 1024 + (lane & 15) * 4) = o;
      }
    }
#pragma unroll
    for (int c = 0; c < 2; ++c) {
      bf16x8 pf[2];
#pragma unroll
      for (int qt = 0; qt < 2; ++qt) {
        int q_ = qt * 16 + lr;
        pf[qt] = *(const bf16x8*)(sP + q_ * 128 + ((c * 64 + lhi * 16) ^ ((q_ & 7) << 4)));
      }
#pragma unroll
      for (int dt = 0; dt < 4; ++dt) {
        int d_ = dt * 16 + lr;
        bf16x8 vf = *(const bf16x8*)&VT[hb + ((size_t)d_ << 10) +
                                        wid * 256 + t * 64 + c * 32 + lhi * 8];
        oaccT[dt][0] = MFMA16(vf, pf[0], oaccT[dt][0]);
        oaccT[dt][1] = MFMA16(vf, pf[1], oaccT[dt][1]);
      }
    }
  }

  __syncthreads();
  float* sAO = (float*)smem;
#pragma unroll
  for (int dt = 0; dt < 4; ++dt)
#pragma unroll
    for (int qt = 0; qt < 2; ++qt)
#pragma unroll
      for (int r = 0; r < 4; ++r) {
        int q_ = qt * 16 + lr;
        int d_ = dt * 16 + lhi * 4 + r;
        sAO[wid * 1056 + q_ * 33 + d_] = oaccT[dt][qt][r];
      }
  __syncthreads();
  {
    int q_ = tid >> 3;
    int d0 = (tid & 7) * 8;
    bf16x8 o;
#pragma unroll
    for (int e = 0; e < 8; ++e) {
      int d_ = d0 + e;
      float s = sAO[q_ * 33 + d_] + sAO[1056 + q_ * 33 + d_] +
                sAO[2112 + q_ * 33 + d_] + sAO[3168 + q_ * 33 + d_];
      o[e] = (short)f2bf(s);
    }
    *(bf16x8*)&ao[(size_t)(b * 1024 + q0 + q_) * 1024 + hcol + d0] = o;
  }
}

// -------- SACRIFICIAL PROBE: QBLK=16 attn (R10 kernel, outputs discarded) --------
// attn_out is fully rewritten by k_attn afterwards; ao goes to dead scratch.
// Purpose: measure the QBLK=16 structure's duration without correctness risk.
__global__ __launch_bounds__(256) void k_attn_probe(
    const unsigned short* __restrict__ Qc, const unsigned short* __restrict__ Kc,
    const unsigned short* __restrict__ VT, float* __restrict__ attn_out,
    unsigned short* __restrict__ ao) {
  __shared__ __align__(16) char smem[8448];
  __shared__ float red[4][16][2];

  const int tid = threadIdx.x;
  const int wid = tid >> 6, lane = tid & 63;
  const int lr = lane & 15, lhi = lane >> 4;
  const int bid = blockIdx.x;
  const int inner = bid >> 3;
  const int bh = (bid & 7) + ((inner >> 6) << 3);
  const int q0 = (inner & 63) * 16;
  const int b = bh >> 4, h = bh & 15;
  const size_t hb = (size_t)bh << 16;
  const int hcol = h * 64;

  bf16x8 af[2];
#pragma unroll
  for (int kk = 0; kk < 2; ++kk)
    af[kk] = *(const bf16x8*)&Qc[hb + (size_t)(q0 + lr) * 64 + kk * 32 + lhi * 8];

  f32x4 acc[16] = {};
#pragma unroll
  for (int kk = 0; kk < 2; ++kk) {
#pragma unroll
    for (int j = 0; j < 16; ++j) {
      int m = wid * 256 + j * 16 + lr;
      bf16x8 bv = *(const bf16x8*)&Kc[hb + (size_t)m * 64 + kk * 32 + lhi * 8];
      acc[j] = MFMA16(af[kk], bv, acc[j]);
    }
  }

  float mw[4];
#pragma unroll
  for (int r = 0; r < 4; ++r) {
    float m_ = -1e30f;
#pragma unroll
    for (int j = 0; j < 16; ++j) {
      acc[j][r] *= 0.125f;
      m_ = fmaxf(m_, acc[j][r]);
    }
#pragma unroll
    for (int off = 1; off < 16; off <<= 1) m_ = fmaxf(m_, __shfl_xor(m_, off));
    mw[r] = m_;
    float s_ = 0.f;
#pragma unroll
    for (int j = 0; j < 16; ++j) {
      float e = __expf(acc[j][r] - m_);
      acc[j][r] = e;
      s_ += e;
    }
#pragma unroll
    for (int off = 1; off < 16; off <<= 1) s_ += __shfl_xor(s_, off);
    if (lr == 0) {
      int rl = lhi * 4 + r;
      red[wid][rl][0] = m_;
      red[wid][rl][1] = s_;
    }
  }
  __syncthreads();

  float inv[4];
#pragma unroll
  for (int r = 0; r < 4; ++r) {
    int rl = lhi * 4 + r;
    float m0 = red[0][rl][0], m1 = red[1][rl][0],
          m2 = red[2][rl][0], m3 = red[3][rl][0];
    float mg = fmaxf(fmaxf(m0, m1), fmaxf(m2, m3));
    float lg = red[0][rl][1] * __expf(m0 - mg) + red[1][rl][1] * __expf(m1 - mg) +
               red[2][rl][1] * __expf(m2 - mg) + red[3][rl][1] * __expf(m3 - mg);
    inv[r] = __expf(mw[r] - mg) / lg;
  }

  unsigned pb[16][2];
#pragma unroll
  for (int j = 0; j < 16; ++j) {
    pb[j][0] = (unsigned)f2bf(acc[j][0] * inv[0]) |
               ((unsigned)f2bf(acc[j][1] * inv[1]) << 16);
    pb[j][1] = (unsigned)f2bf(acc[j][2] * inv[2]) |
               ((unsigned)f2bf(acc[j][3] * inv[3]) << 16);
  }

  char* sP = smem + wid * 2048;
  f32x4 oaccT[4] = {};

#pragma unroll
  for (int t = 0; t < 4; ++t) {
#pragma unroll
    for (int jl = 0; jl < 4; ++jl) {
      int j = t * 4 + jl;
      int kvl2 = (jl * 16 + lr) * 2;
#pragma unroll
      for (int hp = 0; hp < 2; ++hp) {
        unsigned d = pb[j][hp];
        int qa = lhi * 4 + hp * 2;
        int qb = qa + 1;
        *(unsigned short*)(sP + qa * 128 + (kvl2 ^ ((qa & 7) << 4))) =
            (unsigned short)(d & 0xffff);
        *(unsigned short*)(sP + qb * 128 + (kvl2 ^ ((qb & 7) << 4))) =
            (unsigned short)(d >> 16);
      }
    }
    {
      const float* ab = attn_out + (size_t)bh * 1048576 + (size_t)q0 * 1024 +
                        wid * 256 + t * 64;
#pragma unroll
      for (int s = 0; s < 4; ++s) {
        int row_l = s * 4 + (lane >> 4);
        int kvb = (lane & 15) * 8;
        bf16x4 p = *(const bf16x4*)(sP + row_l * 128 + (kvb ^ ((row_l & 7) << 4)));
        float4 o;
        o.x = bf2f((unsigned short)p[0]);
        o.y = bf2f((unsigned short)p[1]);
        o.z = bf2f((unsigned short)p[2]);
        o.w = bf2f((unsigned short)p[3]);
        *(float4*)((float*)ab + (size_t)row_l * 1024 + (lane & 15) * 4) = o;
      }
    }
#pragma unroll
    for (int c = 0; c < 2; ++c) {
      int q_ = lr;
      bf16x8 pf = *(const bf16x8*)(sP + q_ * 128 + ((c * 64 + lhi * 16) ^ ((q_ & 7) << 4)));
#pragma unroll
      for (int dt = 0; dt < 4; ++dt) {
        int d_ = dt * 16 + lr;
        bf16x8 vf = *(const bf16x8*)&VT[hb + ((size_t)d_ << 10) +
                                        wid * 256 + t * 64 + c * 32 + lhi * 8];
        oaccT[dt] = MFMA16(vf, pf, oaccT[dt]);
      }
    }
  }

  __syncthreads();
  float* sAO = (float*)smem;
#pragma unroll
  for (int dt = 0; dt < 4; ++dt)
#pragma unroll
    for (int r = 0; r < 4; ++r) {
      int q_ = lr;
      int d_ = dt * 16 + lhi * 4 + r;
      sAO[wid * 528 + q_ * 33 + d_] = oaccT[dt][r];
    }
  __syncthreads();
  {
    int q_ = tid >> 4;
    int d0 = (tid & 15) * 4;
    bf16x4 o;
#pragma unroll
    for (int e = 0; e < 4; ++e) {
      int d_ = d0 + e;
      float s = sAO[q_ * 33 + d_] + sAO[528 + q_ * 33 + d_] +
                sAO[1056 + q_ * 33 + d_] + sAO[1584 + q_ * 33 + d_];
      o[e] = (short)f2bf(s);
    }
    *(bf16x4*)&ao[(size_t)(b * 1024 + q0 + q_) * 1024 + hcol + d0] = o;
  }
}

// ---------------- launch ----------------
extern "C" void kernel_launch(void* const* d_in, const int* in_sizes, int n_in,
                              void* d_out, int out_size, void* d_ws, size_t ws_size,
                              hipStream_t stream) {
  (void)in_sizes; (void)n_in; (void)out_size; (void)ws_size;
  const float* x     = (const float*)d_in[0];
  const float* ln1g  = (const float*)d_in[1];
  const float* ln1b  = (const float*)d_in[2];
  const float* qkvw  = (const float*)d_in[3];
  const float* projw = (const float*)d_in[4];
  const float* projb = (const float*)d_in[5];
  const float* g1    = (const float*)d_in[6];
  const float* ln2g  = (const float*)d_in[7];
  const float* ln2b  = (const float*)d_in[8];
  const float* fc1w  = (const float*)d_in[9];
  const float* fc1b  = (const float*)d_in[10];
  const float* fc2w  = (const float*)d_in[11];
  const float* fc2b  = (const float*)d_in[12];
  const float* g2    = (const float*)d_in[13];

  char* ws = (char*)d_ws;
  unsigned short* w_qkv  = (unsigned short*)(ws);              // 6 MB
  unsigned short* w_proj = (unsigned short*)(ws + 6291456);    // 2 MB
  unsigned short* w_fc1  = (unsigned short*)(ws + 8388608);    // 8 MB
  unsigned short* w_fc2  = (unsigned short*)(ws + 16777216);   // 8 MB
  unsigned short* n12    = (unsigned short*)(ws + 25165824);   // 8 MB (n1, later n2)
  unsigned short* Qc     = (unsigned short*)(ws + 33554432);   // 8 MB [bh][kv][d]
  unsigned short* Kc     = (unsigned short*)(ws + 41943040);   // 8 MB [bh][kv][d]
  unsigned short* VT     = (unsigned short*)(ws + 50331648);   // 8 MB [bh][d][kv]
  unsigned short* hbuf   = (unsigned short*)(ws + 33554432);   // 32 MB, overlays Qc..aob
  unsigned short* aob    = (unsigned short*)(ws + 58720256);   // 8 MB
  float*          x1     = (float*)(ws + 67108864);            // 16 MB
  unsigned short* aop    = (unsigned short*)(ws + 92274688);   // 8 MB probe scratch

  float* outx = (float*)d_out;
  float* outattn = outx + (size_t)4096 * 1024;

  k_cvt4<<<12288, 256, 0, stream>>>(qkvw, projw, fc1w, fc2w,
                                    w_qkv, w_proj, w_fc1, w_fc2);

  k_ln<<<4096, 256, 0, stream>>>(x, ln1g, ln1b, n12);
  // qkv: M=4096 N=3072 K=1024 -> 192 blocks of 256^2, de-interleaved epilogue
  k_gemm256<0><<<192, 512, 0, stream>>>(n12, w_qkv, 3072, 1024, 16,
                                        nullptr, Qc, Kc, VT, nullptr);
  // sacrificial probe (outputs discarded; attn_out fully rewritten below)
  k_attn_probe<<<4096, 256, 0, stream>>>(Qc, Kc, VT, outattn, aop);
  // real attention (R9-exact, known good)
  k_attn<<<2048, 256, 0, stream>>>(Qc, Kc, VT, outattn, aob);
  // proj: M=4096 N=1024 K=1024 -> 256 blocks of pipelined 128^2
  k_gemm128p<<<256, 256, 0, stream>>>(aob, w_proj, 1024, 1024, 32,
                                      projb, g1, x, x1);
  k_ln<<<4096, 256, 0, stream>>>(x1, ln2g, ln2b, n12);
  // fc1: M=4096 N=4096 K=1024 -> 256 blocks of 256^2
  k_gemm256<1><<<256, 512, 0, stream>>>(n12, w_fc1, 4096, 1024, 16,
                                        fc1b, nullptr, nullptr, nullptr, hbuf);
  // fc2: M=4096 N=1024 K=4096 -> 256 blocks of pipelined 128^2
  k_gemm128p<<<256, 256, 0, stream>>>(hbuf, w_fc2, 1024, 4096, 32,
                                      fc2b, g2, x1, outx);
}

// Round 12
// 346.020 us; speedup vs baseline: 1.4846x; 1.4846x over previous
//
#include <hip/hip_runtime.h>
#include <math.h>

// ---------------- types / helpers ----------------
typedef __attribute__((ext_vector_type(8))) short bf16x8;
typedef __attribute__((ext_vector_type(4))) short bf16x4;
typedef __attribute__((ext_vector_type(4))) float f32x4;

__device__ __forceinline__ unsigned short f2bf(float f) {
  unsigned u = __builtin_bit_cast(unsigned, f);
  u += 0x7fffu + ((u >> 16) & 1u);           // RNE
  return (unsigned short)(u >> 16);
}
__device__ __forceinline__ float bf2f(unsigned short h) {
  return __builtin_bit_cast(float, (unsigned)h << 16);
}

#define MFMA16(a, b, c) __builtin_amdgcn_mfma_f32_16x16x32_bf16((a), (b), (c), 0, 0, 0)

__device__ __forceinline__ void gload_lds16(const void* g, void* l) {
  __builtin_amdgcn_global_load_lds(
      (const __attribute__((address_space(1))) unsigned*)g,
      (__attribute__((address_space(3))) unsigned*)l, 16, 0, 0);
}

// bijective XCD swizzle (m204)
__device__ __forceinline__ int xcd_swz(int bid, int nwg) {
  int q = nwg >> 3, r = nwg & 7;
  int xcd = bid & 7, off = bid >> 3;
  return (xcd < r ? xcd * (q + 1) : r * (q + 1) + (xcd - r) * q) + off;
}

// ---------------- fused fp32 -> bf16 convert (all 4 weights) ----------------
__global__ __launch_bounds__(256) void k_cvt4(
    const float* __restrict__ wq, const float* __restrict__ wp,
    const float* __restrict__ w1, const float* __restrict__ w2,
    unsigned short* __restrict__ oq, unsigned short* __restrict__ op,
    unsigned short* __restrict__ o1, unsigned short* __restrict__ o2) {
  int bid = blockIdx.x;
  const float* src; unsigned short* dst; int base;
  if (bid < 3072)      { src = wq; dst = oq; base = bid; }
  else if (bid < 4096) { src = wp; dst = op; base = bid - 3072; }
  else if (bid < 8192) { src = w1; dst = o1; base = bid - 4096; }
  else                 { src = w2; dst = o2; base = bid - 8192; }
  int i = base * 256 + threadIdx.x;
  float4 v = ((const float4*)src)[i];
  bf16x4 o;
  o[0] = (short)f2bf(v.x); o[1] = (short)f2bf(v.y);
  o[2] = (short)f2bf(v.z); o[3] = (short)f2bf(v.w);
  *(bf16x4*)(dst + (size_t)i * 4) = o;
}

// ---------------- layernorm (1024 cols, 1 block/row) -> bf16 ----------------
__global__ __launch_bounds__(256) void k_ln(const float* __restrict__ x,
                                            const float* __restrict__ g,
                                            const float* __restrict__ b,
                                            unsigned short* __restrict__ out) {
  __shared__ float red[8];
  const int tid = threadIdx.x;
  const size_t row = blockIdx.x;
  float4 v = ((const float4*)(x + row * 1024))[tid];
  float s = v.x + v.y + v.z + v.w;
#pragma unroll
  for (int off = 32; off; off >>= 1) s += __shfl_xor(s, off);
  if ((tid & 63) == 0) red[tid >> 6] = s;
  __syncthreads();
  float mu = (red[0] + red[1] + red[2] + red[3]) * (1.0f / 1024.0f);
  float dx = v.x - mu, dy = v.y - mu, dz = v.z - mu, dw = v.w - mu;
  float s2 = dx * dx + dy * dy + dz * dz + dw * dw;
#pragma unroll
  for (int off = 32; off; off >>= 1) s2 += __shfl_xor(s2, off);
  if ((tid & 63) == 0) red[4 + (tid >> 6)] = s2;
  __syncthreads();
  float var = (red[4] + red[5] + red[6] + red[7]) * (1.0f / 1024.0f);
  float rstd = rsqrtf(var + 1e-5f);
  float4 gv = ((const float4*)g)[tid];
  float4 bv = ((const float4*)b)[tid];
  bf16x4 o;
  o[0] = (short)f2bf(dx * rstd * gv.x + bv.x);
  o[1] = (short)f2bf(dy * rstd * gv.y + bv.y);
  o[2] = (short)f2bf(dz * rstd * gv.z + bv.z);
  o[3] = (short)f2bf(dw * rstd * gv.w + bv.w);
  *(bf16x4*)(out + row * 1024 + tid * 4) = o;
}

// ======== 128x128 PIPELINED GEMM (4-phase counted-vmcnt), templated epilogue ========
// 256 thr = 4 waves (2M x 2N), per-wave 64x64, BK=64, 2 LDS bufs (64 KB).
// EPI 0: qkv de-interleave -> Qc/Kc [bh][kv][d], VT [bh][d][kv] (bf16x4, free transpose)
// EPI 1: bias + exact GELU -> bf16 row-major
// EPI 2: resid + (v + bias)*gamma -> f32
template <int EPI>
__global__ __launch_bounds__(256) void k_gemm128p(
    const unsigned short* __restrict__ A, const unsigned short* __restrict__ Bw,
    int Ndim, int K, int nby,
    const float* __restrict__ bias, const float* __restrict__ gamma,
    const float* __restrict__ resid, float* __restrict__ outf,
    unsigned short* __restrict__ outb,
    unsigned short* __restrict__ Qc, unsigned short* __restrict__ Kc,
    unsigned short* __restrict__ VTo) {
  __shared__ __align__(16) unsigned short lds[2][2][8192];  // [buf][A|B][128*64]

  const int tid = threadIdx.x;
  const int wid = tid >> 6, lane = tid & 63;
  const int wm = wid >> 1, wn = wid & 1;
  const int lr = lane & 15, lhi = lane >> 4;

  const int swz = xcd_swz(blockIdx.x, gridDim.x);
  const int bcol = swz / nby, brow = swz % nby;

  const size_t a_base = (size_t)brow * 128 * K;
  const size_t b_base = (size_t)bcol * 128 * K;
  const int NT = K >> 6;

  auto STAGE = [&](int dbuf, int kt, int which) {
    int ktc = (kt < NT) ? kt : 0;
    int isB = which & 1;
    int odd = which >> 1;
    const unsigned short* src = isB ? (Bw + b_base) : (A + a_base);
    int col = (ktc << 6) + (((lane & 7) ^ ((lane >> 3) & 7)) << 3);
#pragma unroll
    for (int c = 0; c < 2; ++c) {
      int idx = (wid << 1) | c;                            // 0..7
      int chunk = (idx & 3) + ((idx >> 2) << 3) + (odd << 2);
      int row = (chunk << 3) + (lane >> 3);
      gload_lds16(src + (size_t)row * K + col,
                  &lds[dbuf][isB][chunk * 512 + lane * 8]);
    }
  };

  STAGE(0, 0, 0); STAGE(0, 0, 1); STAGE(0, 0, 2); STAGE(0, 0, 3);

  f32x4 acc[4][4] = {};                   // [(i>>1)*32+(i&1)*16][(j>>1)*32+(j&1)*16]
  bf16x8 aF0[2][2], aF1[2][2], bF0[2][2], bF1[2][2];

  const int colx0 = (lhi << 4) ^ ((lr & 7) << 4);
  const int colx1 = (64 + (lhi << 4)) ^ ((lr & 7) << 4);

  for (int t = 0; t < NT; ++t) {
    const int buf = t & 1;
    const char* sAb = (const char*)&lds[buf][0][0];
    const char* sBb = (const char*)&lds[buf][1][0];
#pragma unroll
    for (int q = 0; q < 4; ++q) {
      asm volatile("s_waitcnt vmcnt(6)" ::: "memory");
      __builtin_amdgcn_s_barrier();
      if (q == 0) {
#pragma unroll
        for (int m = 0; m < 2; ++m) {
          int ro = (wm * 64 + m * 16 + lr) * 128;
          aF0[m][0] = *(const bf16x8*)(sAb + ro + colx0);
          aF0[m][1] = *(const bf16x8*)(sAb + ro + colx1);
        }
      } else if (q == 1) {
#pragma unroll
        for (int n = 0; n < 2; ++n) {
          int ro = (wn * 64 + n * 16 + lr) * 128;
          bF0[n][0] = *(const bf16x8*)(sBb + ro + colx0);
          bF0[n][1] = *(const bf16x8*)(sBb + ro + colx1);
        }
      } else if (q == 2) {
#pragma unroll
        for (int m = 0; m < 2; ++m) {
          int ro = (wm * 64 + 32 + m * 16 + lr) * 128;
          aF1[m][0] = *(const bf16x8*)(sAb + ro + colx0);
          aF1[m][1] = *(const bf16x8*)(sAb + ro + colx1);
        }
      } else {
#pragma unroll
        for (int n = 0; n < 2; ++n) {
          int ro = (wn * 64 + 32 + n * 16 + lr) * 128;
          bF1[n][0] = *(const bf16x8*)(sBb + ro + colx0);
          bF1[n][1] = *(const bf16x8*)(sBb + ro + colx1);
        }
      }
      STAGE(buf ^ 1, t + 1, q);
      asm volatile("s_waitcnt lgkmcnt(0)" ::: "memory");
      __builtin_amdgcn_sched_barrier(0);
      __builtin_amdgcn_s_setprio(1);
      if (q == 0) {
        if (t > 0) {
#pragma unroll
          for (int m = 0; m < 2; ++m)
#pragma unroll
            for (int n = 0; n < 2; ++n)
#pragma unroll
              for (int kk = 0; kk < 2; ++kk)
                acc[2 + m][2 + n] = MFMA16(aF1[m][kk], bF1[n][kk], acc[2 + m][2 + n]);
        }
      } else if (q == 1) {
#pragma unroll
        for (int m = 0; m < 2; ++m)
#pragma unroll
          for (int n = 0; n < 2; ++n)
#pragma unroll
            for (int kk = 0; kk < 2; ++kk)
              acc[m][n] = MFMA16(aF0[m][kk], bF0[n][kk], acc[m][n]);
      } else if (q == 2) {
#pragma unroll
        for (int m = 0; m < 2; ++m)
#pragma unroll
          for (int n = 0; n < 2; ++n)
#pragma unroll
            for (int kk = 0; kk < 2; ++kk)
              acc[2 + m][n] = MFMA16(aF1[m][kk], bF0[n][kk], acc[2 + m][n]);
      } else {
#pragma unroll
        for (int m = 0; m < 2; ++m)
#pragma unroll
          for (int n = 0; n < 2; ++n)
#pragma unroll
            for (int kk = 0; kk < 2; ++kk)
              acc[m][2 + n] = MFMA16(aF0[m][kk], bF1[n][kk], acc[m][2 + n]);
      }
      __builtin_amdgcn_s_setprio(0);
    }
  }
#pragma unroll
  for (int m = 0; m < 2; ++m)
#pragma unroll
    for (int n = 0; n < 2; ++n)
#pragma unroll
      for (int kk = 0; kk < 2; ++kk)
        acc[2 + m][2 + n] = MFMA16(aF1[m][kk], bF1[n][kk], acc[2 + m][2 + n]);

  // ---- epilogue ----
  if (EPI == 0) {
    // wave spans cols [bcol*128 + wn*64, +64) = exactly one head column
    const int hc = bcol * 2 + wn;          // 0..47
    const int region = hc >> 4;            // 0=Q, 1=K, 2=V (wave-uniform)
    const int h = hc & 15;
    if (region < 2) {
      unsigned short* dst = (region == 0) ? Qc : Kc;  // [bh][kv][d]
#pragma unroll
      for (int i = 0; i < 4; ++i)
#pragma unroll
        for (int j = 0; j < 4; ++j) {
          int d = (j >> 1) * 32 + (j & 1) * 16 + lr;
#pragma unroll
          for (int r = 0; r < 4; ++r) {
            int row = brow * 128 + wm * 64 + (i >> 1) * 32 + (i & 1) * 16 + lhi * 4 + r;
            int b = row >> 10, kv = row & 1023;
            dst[((size_t)((b << 4) + h) << 16) + (size_t)kv * 64 + d] =
                f2bf(acc[i][j][r]);
          }
        }
    } else {
      // V transposed: VT[bh][d][kv]; r=0..3 kv-consecutive -> bf16x4 store
#pragma unroll
      for (int i = 0; i < 4; ++i)
#pragma unroll
        for (int j = 0; j < 4; ++j) {
          int d = (j >> 1) * 32 + (j & 1) * 16 + lr;
          int row0_ = brow * 128 + wm * 64 + (i >> 1) * 32 + (i & 1) * 16 + lhi * 4;
          int b = row0_ >> 10, kv0 = row0_ & 1023;
          bf16x4 o;
          o[0] = (short)f2bf(acc[i][j][0]);
          o[1] = (short)f2bf(acc[i][j][1]);
          o[2] = (short)f2bf(acc[i][j][2]);
          o[3] = (short)f2bf(acc[i][j][3]);
          *(bf16x4*)&VTo[((size_t)((b << 4) + h) << 16) + ((size_t)d << 10) + kv0] = o;
        }
    }
  } else {
#pragma unroll
    for (int i = 0; i < 4; ++i)
#pragma unroll
      for (int j = 0; j < 4; ++j) {
        int col = bcol * 128 + wn * 64 + (j >> 1) * 32 + (j & 1) * 16 + lr;
        float bi = bias[col];
        float gm = (EPI == 2) ? gamma[col] : 0.0f;
#pragma unroll
        for (int r = 0; r < 4; ++r) {
          int row = brow * 128 + wm * 64 + (i >> 1) * 32 + (i & 1) * 16 + lhi * 4 + r;
          if (EPI == 1) {
            float v = acc[i][j][r] + bi;
            v = 0.5f * v * (1.0f + erff(v * 0.70710678118654752f));
            outb[(size_t)row * Ndim + col] = f2bf(v);
          } else {
            outf[(size_t)row * Ndim + col] =
                resid[(size_t)row * Ndim + col] + (acc[i][j][r] + bi) * gm;
          }
        }
      }
  }
}

// ---------------- fused attention v7 (R9-exact, known good) ----------------
__global__ __launch_bounds__(256) void k_attn(const unsigned short* __restrict__ Qc,
                                              const unsigned short* __restrict__ Kc,
                                              const unsigned short* __restrict__ VT,
                                              float* __restrict__ attn_out,
                                              unsigned short* __restrict__ ao) {
  __shared__ __align__(16) char smem[16896];  // sP 4x4096; sAO overlays
  __shared__ float red[4][32][2];             // [wave][q-row][m,l]

  const int tid = threadIdx.x;
  const int wid = tid >> 6, lane = tid & 63;
  const int lr = lane & 15, lhi = lane >> 4;
  const int bid = blockIdx.x;
  const int bh = (bid & 7) + ((bid >> 8) << 3);   // XCD affinity: head -> one XCD
  const int q0 = ((bid >> 3) & 31) * 32;
  const int b = bh >> 4, h = bh & 15;
  const size_t hb = (size_t)bh << 16;  // per-head base (1024*64 elems)
  const int hcol = h * 64;

  bf16x8 af[2][2];
#pragma unroll
  for (int i = 0; i < 2; ++i)
#pragma unroll
    for (int kk = 0; kk < 2; ++kk)
      af[i][kk] = *(const bf16x8*)&Qc[hb + (size_t)(q0 + i * 16 + lr) * 64 +
                                      kk * 32 + lhi * 8];

  f32x4 acc[2][16] = {};
#pragma unroll
  for (int kk = 0; kk < 2; ++kk) {
#pragma unroll
    for (int j = 0; j < 16; ++j) {
      int m = wid * 256 + j * 16 + lr;
      bf16x8 bv = *(const bf16x8*)&Kc[hb + (size_t)m * 64 + kk * 32 + lhi * 8];
      acc[0][j] = MFMA16(af[0][kk], bv, acc[0][j]);
      acc[1][j] = MFMA16(af[1][kk], bv, acc[1][j]);
    }
  }

  float mw[2][4];
#pragma unroll
  for (int i = 0; i < 2; ++i)
#pragma unroll
    for (int r = 0; r < 4; ++r) {
      float m_ = -1e30f;
#pragma unroll
      for (int j = 0; j < 16; ++j) {
        acc[i][j][r] *= 0.125f;
        m_ = fmaxf(m_, acc[i][j][r]);
      }
#pragma unroll
      for (int off = 1; off < 16; off <<= 1) m_ = fmaxf(m_, __shfl_xor(m_, off));
      mw[i][r] = m_;
      float s_ = 0.f;
#pragma unroll
      for (int j = 0; j < 16; ++j) {
        float e = __expf(acc[i][j][r] - m_);
        acc[i][j][r] = e;
        s_ += e;
      }
#pragma unroll
      for (int off = 1; off < 16; off <<= 1) s_ += __shfl_xor(s_, off);
      if (lr == 0) {
        int rl = i * 16 + lhi * 4 + r;
        red[wid][rl][0] = m_;
        red[wid][rl][1] = s_;
      }
    }
  __syncthreads();

  float inv[2][4];
#pragma unroll
  for (int i = 0; i < 2; ++i)
#pragma unroll
    for (int r = 0; r < 4; ++r) {
      int rl = i * 16 + lhi * 4 + r;
      float m0 = red[0][rl][0], m1 = red[1][rl][0],
            m2 = red[2][rl][0], m3 = red[3][rl][0];
      float mg = fmaxf(fmaxf(m0, m1), fmaxf(m2, m3));
      float lg = red[0][rl][1] * __expf(m0 - mg) + red[1][rl][1] * __expf(m1 - mg) +
                 red[2][rl][1] * __expf(m2 - mg) + red[3][rl][1] * __expf(m3 - mg);
      inv[i][r] = __expf(mw[i][r] - mg) / lg;
    }

  unsigned pb[2][16][2];
#pragma unroll
  for (int i = 0; i < 2; ++i)
#pragma unroll
    for (int j = 0; j < 16; ++j) {
      pb[i][j][0] = (unsigned)f2bf(acc[i][j][0] * inv[i][0]) |
                    ((unsigned)f2bf(acc[i][j][1] * inv[i][1]) << 16);
      pb[i][j][1] = (unsigned)f2bf(acc[i][j][2] * inv[i][2]) |
                    ((unsigned)f2bf(acc[i][j][3] * inv[i][3]) << 16);
    }

  char* sP = smem + wid * 4096;
  f32x4 oaccT[4][2] = {};

#pragma unroll
  for (int t = 0; t < 4; ++t) {
#pragma unroll
    for (int i = 0; i < 2; ++i)
#pragma unroll
      for (int jl = 0; jl < 4; ++jl) {
        int j = t * 4 + jl;
        int kvl2 = (jl * 16 + lr) * 2;
#pragma unroll
        for (int hp = 0; hp < 2; ++hp) {
          unsigned d = pb[i][j][hp];
          int qa = i * 16 + lhi * 4 + hp * 2;
          int qb = qa + 1;
          *(unsigned short*)(sP + qa * 128 + (kvl2 ^ ((qa & 7) << 4))) =
              (unsigned short)(d & 0xffff);
          *(unsigned short*)(sP + qb * 128 + (kvl2 ^ ((qb & 7) << 4))) =
              (unsigned short)(d >> 16);
        }
      }
    {
      const float* ab = attn_out + (size_t)bh * 1048576 + (size_t)q0 * 1024 +
                        wid * 256 + t * 64;
#pragma unroll
      for (int s = 0; s < 8; ++s) {
        int row_l = s * 4 + (lane >> 4);
        int kvb = (lane & 15) * 8;
        bf16x4 p = *(const bf16x4*)(sP + row_l * 128 + (kvb ^ ((row_l & 7) << 4)));
        float4 o;
        o.x = bf2f((unsigned short)p[0]);
        o.y = bf2f((unsigned short)p[1]);
        o.z = bf2f((unsigned short)p[2]);
        o.w = bf2f((unsigned short)p[3]);
        *(float4*)((float*)ab + (size_t)row_l * 1024 + (lane & 15) * 4) = o;
      }
    }
#pragma unroll
    for (int c = 0; c < 2; ++c) {
      bf16x8 pf[2];
#pragma unroll
      for (int qt = 0; qt < 2; ++qt) {
        int q_ = qt * 16 + lr;
        pf[qt] = *(const bf16x8*)(sP + q_ * 128 + ((c * 64 + lhi * 16) ^ ((q_ & 7) << 4)));
      }
#pragma unroll
      for (int dt = 0; dt < 4; ++dt) {
        int d_ = dt * 16 + lr;
        bf16x8 vf = *(const bf16x8*)&VT[hb + ((size_t)d_ << 10) +
                                        wid * 256 + t * 64 + c * 32 + lhi * 8];
        oaccT[dt][0] = MFMA16(vf, pf[0], oaccT[dt][0]);
        oaccT[dt][1] = MFMA16(vf, pf[1], oaccT[dt][1]);
      }
    }
  }

  __syncthreads();
  float* sAO = (float*)smem;
#pragma unroll
  for (int dt = 0; dt < 4; ++dt)
#pragma unroll
    for (int qt = 0; qt < 2; ++qt)
#pragma unroll
      for (int r = 0; r < 4; ++r) {
        int q_ = qt * 16 + lr;
        int d_ = dt * 16 + lhi * 4 + r;
        sAO[wid * 1056 + q_ * 33 + d_] = oaccT[dt][qt][r];
      }
  __syncthreads();
  {
    int q_ = tid >> 3;
    int d0 = (tid & 7) * 8;
    bf16x8 o;
#pragma unroll
    for (int e = 0; e < 8; ++e) {
      int d_ = d0 + e;
      float s = sAO[q_ * 33 + d_] + sAO[1056 + q_ * 33 + d_] +
                sAO[2112 + q_ * 33 + d_] + sAO[3168 + q_ * 33 + d_];
      o[e] = (short)f2bf(s);
    }
    *(bf16x8*)&ao[(size_t)(b * 1024 + q0 + q_) * 1024 + hcol + d0] = o;
  }
}

// ---------------- launch ----------------
extern "C" void kernel_launch(void* const* d_in, const int* in_sizes, int n_in,
                              void* d_out, int out_size, void* d_ws, size_t ws_size,
                              hipStream_t stream) {
  (void)in_sizes; (void)n_in; (void)out_size; (void)ws_size;
  const float* x     = (const float*)d_in[0];
  const float* ln1g  = (const float*)d_in[1];
  const float* ln1b  = (const float*)d_in[2];
  const float* qkvw  = (const float*)d_in[3];
  const float* projw = (const float*)d_in[4];
  const float* projb = (const float*)d_in[5];
  const float* g1    = (const float*)d_in[6];
  const float* ln2g  = (const float*)d_in[7];
  const float* ln2b  = (const float*)d_in[8];
  const float* fc1w  = (const float*)d_in[9];
  const float* fc1b  = (const float*)d_in[10];
  const float* fc2w  = (const float*)d_in[11];
  const float* fc2b  = (const float*)d_in[12];
  const float* g2    = (const float*)d_in[13];

  char* ws = (char*)d_ws;
  unsigned short* w_qkv  = (unsigned short*)(ws);              // 6 MB
  unsigned short* w_proj = (unsigned short*)(ws + 6291456);    // 2 MB
  unsigned short* w_fc1  = (unsigned short*)(ws + 8388608);    // 8 MB
  unsigned short* w_fc2  = (unsigned short*)(ws + 16777216);   // 8 MB
  unsigned short* n12    = (unsigned short*)(ws + 25165824);   // 8 MB (n1, later n2)
  unsigned short* Qc     = (unsigned short*)(ws + 33554432);   // 8 MB [bh][kv][d]
  unsigned short* Kc     = (unsigned short*)(ws + 41943040);   // 8 MB [bh][kv][d]
  unsigned short* VT     = (unsigned short*)(ws + 50331648);   // 8 MB [bh][d][kv]
  unsigned short* hbuf   = (unsigned short*)(ws + 33554432);   // 32 MB, overlays Qc..aob
  unsigned short* aob    = (unsigned short*)(ws + 58720256);   // 8 MB
  float*          x1     = (float*)(ws + 67108864);            // 16 MB

  float* outx = (float*)d_out;
  float* outattn = outx + (size_t)4096 * 1024;

  k_cvt4<<<12288, 256, 0, stream>>>(qkvw, projw, fc1w, fc2w,
                                    w_qkv, w_proj, w_fc1, w_fc2);

  k_ln<<<4096, 256, 0, stream>>>(x, ln1g, ln1b, n12);
  // qkv: M=4096 N=3072 K=1024 -> 768 blocks of pipelined 128^2, de-interleave epi
  k_gemm128p<0><<<768, 256, 0, stream>>>(n12, w_qkv, 3072, 1024, 32,
                                         nullptr, nullptr, nullptr, nullptr,
                                         nullptr, Qc, Kc, VT);
  k_attn<<<2048, 256, 0, stream>>>(Qc, Kc, VT, outattn, aob);
  // proj: M=4096 N=1024 K=1024 -> 256 blocks of pipelined 128^2
  k_gemm128p<2><<<256, 256, 0, stream>>>(aob, w_proj, 1024, 1024, 32,
                                         projb, g1, x, x1,
                                         nullptr, nullptr, nullptr, nullptr);
  k_ln<<<4096, 256, 0, stream>>>(x1, ln2g, ln2b, n12);
  // fc1: M=4096 N=4096 K=1024 -> 1024 blocks of pipelined 128^2, GELU epi
  k_gemm128p<1><<<1024, 256, 0, stream>>>(n12, w_fc1, 4096, 1024, 32,
                                          fc1b, nullptr, nullptr, nullptr,
                                          hbuf, nullptr, nullptr, nullptr);
  // fc2: M=4096 N=1024 K=4096 -> 256 blocks of pipelined 128^2
  k_gemm128p<2><<<256, 256, 0, stream>>>(hbuf, w_fc2, 1024, 4096, 32,
                                         fc2b, g2, x1, outx,
                                         nullptr, nullptr, nullptr, nullptr);
}

// Round 13
// 335.449 us; speedup vs baseline: 1.5313x; 1.0315x over previous
//
#include <hip/hip_runtime.h>
#include <math.h>

// ---------------- types / helpers ----------------
typedef __attribute__((ext_vector_type(8))) short bf16x8;
typedef __attribute__((ext_vector_type(4))) short bf16x4;
typedef __attribute__((ext_vector_type(4))) float f32x4;

__device__ __forceinline__ unsigned short f2bf(float f) {
  unsigned u = __builtin_bit_cast(unsigned, f);
  u += 0x7fffu + ((u >> 16) & 1u);           // RNE
  return (unsigned short)(u >> 16);
}
__device__ __forceinline__ float bf2f(unsigned short h) {
  return __builtin_bit_cast(float, (unsigned)h << 16);
}

#define MFMA16(a, b, c) __builtin_amdgcn_mfma_f32_16x16x32_bf16((a), (b), (c), 0, 0, 0)

__device__ __forceinline__ void gload_lds16(const void* g, void* l) {
  __builtin_amdgcn_global_load_lds(
      (const __attribute__((address_space(1))) unsigned*)g,
      (__attribute__((address_space(3))) unsigned*)l, 16, 0, 0);
}

// bijective XCD swizzle (m204)
__device__ __forceinline__ int xcd_swz(int bid, int nwg) {
  int q = nwg >> 3, r = nwg & 7;
  int xcd = bid & 7, off = bid >> 3;
  return (xcd < r ? xcd * (q + 1) : r * (q + 1) + (xcd - r) * q) + off;
}

// ---------------- fused fp32 -> bf16 convert (all 4 weights) ----------------
__global__ __launch_bounds__(256) void k_cvt4(
    const float* __restrict__ wq, const float* __restrict__ wp,
    const float* __restrict__ w1, const float* __restrict__ w2,
    unsigned short* __restrict__ oq, unsigned short* __restrict__ op,
    unsigned short* __restrict__ o1, unsigned short* __restrict__ o2) {
  int bid = blockIdx.x;
  const float* src; unsigned short* dst; int base;
  if (bid < 3072)      { src = wq; dst = oq; base = bid; }
  else if (bid < 4096) { src = wp; dst = op; base = bid - 3072; }
  else if (bid < 8192) { src = w1; dst = o1; base = bid - 4096; }
  else                 { src = w2; dst = o2; base = bid - 8192; }
  int i = base * 256 + threadIdx.x;
  float4 v = ((const float4*)src)[i];
  bf16x4 o;
  o[0] = (short)f2bf(v.x); o[1] = (short)f2bf(v.y);
  o[2] = (short)f2bf(v.z); o[3] = (short)f2bf(v.w);
  *(bf16x4*)(dst + (size_t)i * 4) = o;
}

// ---------------- layernorm (1024 cols, 1 block/row) -> bf16 ----------------
__global__ __launch_bounds__(256) void k_ln(const float* __restrict__ x,
                                            const float* __restrict__ g,
                                            const float* __restrict__ b,
                                            unsigned short* __restrict__ out) {
  __shared__ float red[8];
  const int tid = threadIdx.x;
  const size_t row = blockIdx.x;
  float4 v = ((const float4*)(x + row * 1024))[tid];
  float s = v.x + v.y + v.z + v.w;
#pragma unroll
  for (int off = 32; off; off >>= 1) s += __shfl_xor(s, off);
  if ((tid & 63) == 0) red[tid >> 6] = s;
  __syncthreads();
  float mu = (red[0] + red[1] + red[2] + red[3]) * (1.0f / 1024.0f);
  float dx = v.x - mu, dy = v.y - mu, dz = v.z - mu, dw = v.w - mu;
  float s2 = dx * dx + dy * dy + dz * dz + dw * dw;
#pragma unroll
  for (int off = 32; off; off >>= 1) s2 += __shfl_xor(s2, off);
  if ((tid & 63) == 0) red[4 + (tid >> 6)] = s2;
  __syncthreads();
  float var = (red[4] + red[5] + red[6] + red[7]) * (1.0f / 1024.0f);
  float rstd = rsqrtf(var + 1e-5f);
  float4 gv = ((const float4*)g)[tid];
  float4 bv = ((const float4*)b)[tid];
  bf16x4 o;
  o[0] = (short)f2bf(dx * rstd * gv.x + bv.x);
  o[1] = (short)f2bf(dy * rstd * gv.y + bv.y);
  o[2] = (short)f2bf(dz * rstd * gv.z + bv.z);
  o[3] = (short)f2bf(dw * rstd * gv.w + bv.w);
  *(bf16x4*)(out + row * 1024 + tid * 4) = o;
}

// ============ 256x256 multi-phase GEMM (R9-exact): C = A @ B^T ============
template <int EPI>
__global__ __launch_bounds__(512, 2) void k_gemm256(
    const unsigned short* __restrict__ A, const unsigned short* __restrict__ Bw,
    int Ndim, int K, int nby,
    const float* __restrict__ bias,
    unsigned short* __restrict__ Qc, unsigned short* __restrict__ Kc,
    unsigned short* __restrict__ VTo,
    unsigned short* __restrict__ outb) {
  __shared__ __align__(16) unsigned short lds[2][2][16384];  // [buf][A|B][256*64]

  const int tid = threadIdx.x;
  const int wid = tid >> 6, lane = tid & 63;
  const int wm = wid >> 2, wn = wid & 3;
  const int lr = lane & 15, lhi = lane >> 4;

  const int nwg = gridDim.x;
  const int swz = xcd_swz(blockIdx.x, nwg);
  const int bcol = swz / nby, brow = swz % nby;

  const size_t a_base = (size_t)brow * 256 * K;
  const size_t b_base = (size_t)bcol * 256 * K;
  const int NT = K >> 6;

  auto STAGE = [&](int dbuf, int kt, int which) {
    int ktc = (kt < NT) ? kt : 0;
    int isB = which & 1;
    int odd = which >> 1;
    const unsigned short* src = isB ? (Bw + b_base) : (A + a_base);
    int col = (ktc << 6) + (((lane & 7) ^ ((lane >> 3) & 7)) << 3);
#pragma unroll
    for (int c = 0; c < 2; ++c) {
      int idx = (wid << 1) | c;
      int chunk = isB ? ((idx & 3) + ((idx >> 2) << 3) + (odd << 2))
                      : ((idx & 7) + ((idx >> 3) << 4) + (odd << 3));
      int row = (chunk << 3) + (lane >> 3);
      gload_lds16(src + (size_t)row * K + col,
                  &lds[dbuf][isB][chunk * 512 + lane * 8]);
    }
  };

  STAGE(0, 0, 0); STAGE(0, 0, 1); STAGE(0, 0, 2); STAGE(0, 0, 3);

  f32x4 acc[8][4] = {};
  bf16x8 aF0[4][2], aF1[4][2], bF0[2][2], bF1[2][2];

  const int colx0 = (lhi << 4) ^ ((lr & 7) << 4);
  const int colx1 = (64 + (lhi << 4)) ^ ((lr & 7) << 4);

  for (int t = 0; t < NT; ++t) {
    const int buf = t & 1;
    const char* sAb = (const char*)&lds[buf][0][0];
    const char* sBb = (const char*)&lds[buf][1][0];
#pragma unroll
    for (int q = 0; q < 4; ++q) {
      asm volatile("s_waitcnt vmcnt(6)" ::: "memory");
      __builtin_amdgcn_s_barrier();
      if (q == 0) {
#pragma unroll
        for (int m = 0; m < 4; ++m) {
          int ro = (wm * 128 + m * 16 + lr) * 128;
          aF0[m][0] = *(const bf16x8*)(sAb + ro + colx0);
          aF0[m][1] = *(const bf16x8*)(sAb + ro + colx1);
        }
      } else if (q == 1) {
#pragma unroll
        for (int n = 0; n < 2; ++n) {
          int ro = (wn * 64 + n * 16 + lr) * 128;
          bF0[n][0] = *(const bf16x8*)(sBb + ro + colx0);
          bF0[n][1] = *(const bf16x8*)(sBb + ro + colx1);
        }
      } else if (q == 2) {
#pragma unroll
        for (int m = 0; m < 4; ++m) {
          int ro = (wm * 128 + 64 + m * 16 + lr) * 128;
          aF1[m][0] = *(const bf16x8*)(sAb + ro + colx0);
          aF1[m][1] = *(const bf16x8*)(sAb + ro + colx1);
        }
      } else {
#pragma unroll
        for (int n = 0; n < 2; ++n) {
          int ro = (wn * 64 + 32 + n * 16 + lr) * 128;
          bF1[n][0] = *(const bf16x8*)(sBb + ro + colx0);
          bF1[n][1] = *(const bf16x8*)(sBb + ro + colx1);
        }
      }
      STAGE(buf ^ 1, t + 1, q);
      asm volatile("s_waitcnt lgkmcnt(0)" ::: "memory");
      __builtin_amdgcn_sched_barrier(0);
      __builtin_amdgcn_s_setprio(1);
      if (q == 0) {
        if (t > 0) {
#pragma unroll
          for (int m = 0; m < 4; ++m)
#pragma unroll
            for (int n = 0; n < 2; ++n)
#pragma unroll
              for (int kk = 0; kk < 2; ++kk)
                acc[4 + m][2 + n] = MFMA16(aF1[m][kk], bF1[n][kk], acc[4 + m][2 + n]);
        }
      } else if (q == 1) {
#pragma unroll
        for (int m = 0; m < 4; ++m)
#pragma unroll
          for (int n = 0; n < 2; ++n)
#pragma unroll
            for (int kk = 0; kk < 2; ++kk)
              acc[m][n] = MFMA16(aF0[m][kk], bF0[n][kk], acc[m][n]);
      } else if (q == 2) {
#pragma unroll
        for (int m = 0; m < 4; ++m)
#pragma unroll
          for (int n = 0; n < 2; ++n)
#pragma unroll
            for (int kk = 0; kk < 2; ++kk)
              acc[4 + m][n] = MFMA16(aF1[m][kk], bF0[n][kk], acc[4 + m][n]);
      } else {
#pragma unroll
        for (int m = 0; m < 4; ++m)
#pragma unroll
          for (int n = 0; n < 2; ++n)
#pragma unroll
            for (int kk = 0; kk < 2; ++kk)
              acc[m][2 + n] = MFMA16(aF0[m][kk], bF1[n][kk], acc[m][2 + n]);
      }
      __builtin_amdgcn_s_setprio(0);
    }
  }
#pragma unroll
  for (int m = 0; m < 4; ++m)
#pragma unroll
    for (int n = 0; n < 2; ++n)
#pragma unroll
      for (int kk = 0; kk < 2; ++kk)
        acc[4 + m][2 + n] = MFMA16(aF1[m][kk], bF1[n][kk], acc[4 + m][2 + n]);

  // ---- epilogue ----
  if (EPI == 0) {
    const int region = bcol >> 2;          // 0=Q, 1=K, 2=V (uniform)
    const int h = (bcol & 3) * 4 + wn;
    if (region < 2) {
      unsigned short* dst = (region == 0) ? Qc : Kc;  // [bh][kv][d]
#pragma unroll
      for (int m = 0; m < 8; ++m)
#pragma unroll
        for (int n = 0; n < 4; ++n) {
          int d = n * 16 + lr;
#pragma unroll
          for (int r = 0; r < 4; ++r) {
            int row = brow * 256 + wm * 128 + m * 16 + lhi * 4 + r;
            int b = row >> 10, kv = row & 1023;
            dst[((size_t)((b << 4) + h) << 16) + (size_t)kv * 64 + d] =
                f2bf(acc[m][n][r]);
          }
        }
    } else {
#pragma unroll
      for (int m = 0; m < 8; ++m)
#pragma unroll
        for (int n = 0; n < 4; ++n) {
          int d = n * 16 + lr;
          int row0_ = brow * 256 + wm * 128 + m * 16 + lhi * 4;
          int b = row0_ >> 10, kv0 = row0_ & 1023;
          bf16x4 o;
          o[0] = (short)f2bf(acc[m][n][0]);
          o[1] = (short)f2bf(acc[m][n][1]);
          o[2] = (short)f2bf(acc[m][n][2]);
          o[3] = (short)f2bf(acc[m][n][3]);
          *(bf16x4*)&VTo[((size_t)((b << 4) + h) << 16) + ((size_t)d << 10) + kv0] = o;
        }
    }
  } else {
#pragma unroll
    for (int m = 0; m < 8; ++m)
#pragma unroll
      for (int n = 0; n < 4; ++n) {
        int col = bcol * 256 + wn * 64 + n * 16 + lr;
        float bi = bias[col];
#pragma unroll
        for (int r = 0; r < 4; ++r) {
          int row = brow * 256 + wm * 128 + m * 16 + lhi * 4 + r;
          float v = acc[m][n][r] + bi;
          v = 0.5f * v * (1.0f + erff(v * 0.70710678118654752f));
          outb[(size_t)row * Ndim + col] = f2bf(v);
        }
      }
  }
}

// ======== 128x128 PIPELINED GEMM (4-phase counted-vmcnt) — R9-exact ========
__global__ __launch_bounds__(256) void k_gemm128p(
    const unsigned short* __restrict__ A, const unsigned short* __restrict__ Bw,
    int Ndim, int K, int nby,
    const float* __restrict__ bias, const float* __restrict__ gamma,
    const float* __restrict__ resid, float* __restrict__ outf) {
  __shared__ __align__(16) unsigned short lds[2][2][8192];  // [buf][A|B][128*64]

  const int tid = threadIdx.x;
  const int wid = tid >> 6, lane = tid & 63;
  const int wm = wid >> 1, wn = wid & 1;
  const int lr = lane & 15, lhi = lane >> 4;

  const int swz = xcd_swz(blockIdx.x, gridDim.x);
  const int bcol = swz / nby, brow = swz % nby;

  const size_t a_base = (size_t)brow * 128 * K;
  const size_t b_base = (size_t)bcol * 128 * K;
  const int NT = K >> 6;

  auto STAGE = [&](int dbuf, int kt, int which) {
    int ktc = (kt < NT) ? kt : 0;
    int isB = which & 1;
    int odd = which >> 1;
    const unsigned short* src = isB ? (Bw + b_base) : (A + a_base);
    int col = (ktc << 6) + (((lane & 7) ^ ((lane >> 3) & 7)) << 3);
#pragma unroll
    for (int c = 0; c < 2; ++c) {
      int idx = (wid << 1) | c;                            // 0..7
      int chunk = (idx & 3) + ((idx >> 2) << 3) + (odd << 2);
      int row = (chunk << 3) + (lane >> 3);
      gload_lds16(src + (size_t)row * K + col,
                  &lds[dbuf][isB][chunk * 512 + lane * 8]);
    }
  };

  STAGE(0, 0, 0); STAGE(0, 0, 1); STAGE(0, 0, 2); STAGE(0, 0, 3);

  f32x4 acc[4][4] = {};
  bf16x8 aF0[2][2], aF1[2][2], bF0[2][2], bF1[2][2];

  const int colx0 = (lhi << 4) ^ ((lr & 7) << 4);
  const int colx1 = (64 + (lhi << 4)) ^ ((lr & 7) << 4);

  for (int t = 0; t < NT; ++t) {
    const int buf = t & 1;
    const char* sAb = (const char*)&lds[buf][0][0];
    const char* sBb = (const char*)&lds[buf][1][0];
#pragma unroll
    for (int q = 0; q < 4; ++q) {
      asm volatile("s_waitcnt vmcnt(6)" ::: "memory");
      __builtin_amdgcn_s_barrier();
      if (q == 0) {
#pragma unroll
        for (int m = 0; m < 2; ++m) {
          int ro = (wm * 64 + m * 16 + lr) * 128;
          aF0[m][0] = *(const bf16x8*)(sAb + ro + colx0);
          aF0[m][1] = *(const bf16x8*)(sAb + ro + colx1);
        }
      } else if (q == 1) {
#pragma unroll
        for (int n = 0; n < 2; ++n) {
          int ro = (wn * 64 + n * 16 + lr) * 128;
          bF0[n][0] = *(const bf16x8*)(sBb + ro + colx0);
          bF0[n][1] = *(const bf16x8*)(sBb + ro + colx1);
        }
      } else if (q == 2) {
#pragma unroll
        for (int m = 0; m < 2; ++m) {
          int ro = (wm * 64 + 32 + m * 16 + lr) * 128;
          aF1[m][0] = *(const bf16x8*)(sAb + ro + colx0);
          aF1[m][1] = *(const bf16x8*)(sAb + ro + colx1);
        }
      } else {
#pragma unroll
        for (int n = 0; n < 2; ++n) {
          int ro = (wn * 64 + 32 + n * 16 + lr) * 128;
          bF1[n][0] = *(const bf16x8*)(sBb + ro + colx0);
          bF1[n][1] = *(const bf16x8*)(sBb + ro + colx1);
        }
      }
      STAGE(buf ^ 1, t + 1, q);
      asm volatile("s_waitcnt lgkmcnt(0)" ::: "memory");
      __builtin_amdgcn_sched_barrier(0);
      __builtin_amdgcn_s_setprio(1);
      if (q == 0) {
        if (t > 0) {
#pragma unroll
          for (int m = 0; m < 2; ++m)
#pragma unroll
            for (int n = 0; n < 2; ++n)
#pragma unroll
              for (int kk = 0; kk < 2; ++kk)
                acc[2 + m][2 + n] = MFMA16(aF1[m][kk], bF1[n][kk], acc[2 + m][2 + n]);
        }
      } else if (q == 1) {
#pragma unroll
        for (int m = 0; m < 2; ++m)
#pragma unroll
          for (int n = 0; n < 2; ++n)
#pragma unroll
            for (int kk = 0; kk < 2; ++kk)
              acc[m][n] = MFMA16(aF0[m][kk], bF0[n][kk], acc[m][n]);
      } else if (q == 2) {
#pragma unroll
        for (int m = 0; m < 2; ++m)
#pragma unroll
          for (int n = 0; n < 2; ++n)
#pragma unroll
            for (int kk = 0; kk < 2; ++kk)
              acc[2 + m][n] = MFMA16(aF1[m][kk], bF0[n][kk], acc[2 + m][n]);
      } else {
#pragma unroll
        for (int m = 0; m < 2; ++m)
#pragma unroll
          for (int n = 0; n < 2; ++n)
#pragma unroll
            for (int kk = 0; kk < 2; ++kk)
              acc[m][2 + n] = MFMA16(aF0[m][kk], bF1[n][kk], acc[m][2 + n]);
      }
      __builtin_amdgcn_s_setprio(0);
    }
  }
#pragma unroll
  for (int m = 0; m < 2; ++m)
#pragma unroll
    for (int n = 0; n < 2; ++n)
#pragma unroll
      for (int kk = 0; kk < 2; ++kk)
        acc[2 + m][2 + n] = MFMA16(aF1[m][kk], bF1[n][kk], acc[2 + m][2 + n]);

  // ---- epilogue: resid + (v + bias)*gamma -> f32 ----
#pragma unroll
  for (int i = 0; i < 4; ++i)
#pragma unroll
    for (int j = 0; j < 4; ++j) {
      int col = bcol * 128 + wn * 64 + (j >> 1) * 32 + (j & 1) * 16 + lr;
      float bi = bias[col], gm = gamma[col];
#pragma unroll
      for (int r = 0; r < 4; ++r) {
        int row = brow * 128 + wm * 64 + (i >> 1) * 32 + (i & 1) * 16 + lhi * 4 + r;
        outf[(size_t)row * Ndim + col] =
            resid[(size_t)row * Ndim + col] + (acc[i][j][r] + bi) * gm;
      }
    }
}

// ---------------- fused attention v9: 512 thr / 8 waves, 128 kv per wave ----------------
// Same index algebra as v7 (QBLK=32, rl = i*16+lhi*4+r); only wid range (0..7),
// kv slice (wid*128), j loops (8), t loops (2), 8-way combine/reduce differ.
__global__ __launch_bounds__(512) void k_attn(const unsigned short* __restrict__ Qc,
                                              const unsigned short* __restrict__ Kc,
                                              const unsigned short* __restrict__ VT,
                                              float* __restrict__ attn_out,
                                              unsigned short* __restrict__ ao) {
  __shared__ __align__(16) char smem[33792];  // sP 8x4096 = 32768; sAO [8][32][33]*4 = 33792
  __shared__ float red[8][32][2];             // [wave][q-row][m,l]

  const int tid = threadIdx.x;
  const int wid = tid >> 6, lane = tid & 63;  // wid 0..7
  const int lr = lane & 15, lhi = lane >> 4;
  const int bid = blockIdx.x;
  const int bh = (bid & 7) + ((bid >> 8) << 3);   // XCD affinity: head -> one XCD
  const int q0 = ((bid >> 3) & 31) * 32;
  const int b = bh >> 4, h = bh & 15;
  const size_t hb = (size_t)bh << 16;  // per-head base (1024*64 elems)
  const int hcol = h * 64;

  // ---- Q fragments (same 32 q rows in every wave) ----
  bf16x8 af[2][2];
#pragma unroll
  for (int i = 0; i < 2; ++i)
#pragma unroll
    for (int kk = 0; kk < 2; ++kk)
      af[i][kk] = *(const bf16x8*)&Qc[hb + (size_t)(q0 + i * 16 + lr) * 64 +
                                      kk * 32 + lhi * 8];

  // ---- S = Q K^T : wave covers kv [wid*128, +128) ----
  f32x4 acc[2][8] = {};
#pragma unroll
  for (int kk = 0; kk < 2; ++kk) {
#pragma unroll
    for (int j = 0; j < 8; ++j) {
      int m = wid * 128 + j * 16 + lr;
      bf16x8 bv = *(const bf16x8*)&Kc[hb + (size_t)m * 64 + kk * 32 + lhi * 8];
      acc[0][j] = MFMA16(af[0][kk], bv, acc[0][j]);
      acc[1][j] = MFMA16(af[1][kk], bv, acc[1][j]);
    }
  }

  // ---- softmax, flash-combine across 8 waves; ONE barrier ----
  float mw[2][4];
#pragma unroll
  for (int i = 0; i < 2; ++i)
#pragma unroll
    for (int r = 0; r < 4; ++r) {
      float m_ = -1e30f;
#pragma unroll
      for (int j = 0; j < 8; ++j) {
        acc[i][j][r] *= 0.125f;
        m_ = fmaxf(m_, acc[i][j][r]);
      }
#pragma unroll
      for (int off = 1; off < 16; off <<= 1) m_ = fmaxf(m_, __shfl_xor(m_, off));
      mw[i][r] = m_;
      float s_ = 0.f;
#pragma unroll
      for (int j = 0; j < 8; ++j) {
        float e = __expf(acc[i][j][r] - m_);
        acc[i][j][r] = e;  // acc now holds exp(s - m_w)
        s_ += e;
      }
#pragma unroll
      for (int off = 1; off < 16; off <<= 1) s_ += __shfl_xor(s_, off);
      if (lr == 0) {
        int rl = i * 16 + lhi * 4 + r;
        red[wid][rl][0] = m_;
        red[wid][rl][1] = s_;
      }
    }
  __syncthreads();

  // combine: inv = exp(m_w - m_g) / l_g  (8 waves)
  float inv[2][4];
#pragma unroll
  for (int i = 0; i < 2; ++i)
#pragma unroll
    for (int r = 0; r < 4; ++r) {
      int rl = i * 16 + lhi * 4 + r;
      float mg = -1e30f;
#pragma unroll
      for (int k = 0; k < 8; ++k) mg = fmaxf(mg, red[k][rl][0]);
      float lg = 0.f;
#pragma unroll
      for (int k = 0; k < 8; ++k) lg += red[k][rl][1] * __expf(red[k][rl][0] - mg);
      inv[i][r] = __expf(mw[i][r] - mg) / lg;
    }

  // ---- normalize into packed bf16 P (registers only) ----
  unsigned pb[2][8][2];
#pragma unroll
  for (int i = 0; i < 2; ++i)
#pragma unroll
    for (int j = 0; j < 8; ++j) {
      pb[i][j][0] = (unsigned)f2bf(acc[i][j][0] * inv[i][0]) |
                    ((unsigned)f2bf(acc[i][j][1] * inv[i][1]) << 16);
      pb[i][j][1] = (unsigned)f2bf(acc[i][j][2] * inv[i][2]) |
                    ((unsigned)f2bf(acc[i][j][3] * inv[i][3]) << 16);
    }

  // ---- PV + attn_out stores, 2 sub-tiles of 64 kv ----
  char* sP = smem + wid * 4096;   // [32 q][64 kv] bf16, swizzled 128B rows
  f32x4 oaccT[4][2] = {};         // [dt][qt] -> D[d][q]

#pragma unroll
  for (int t = 0; t < 2; ++t) {
    // (a) write sP sub-tile from pb
#pragma unroll
    for (int i = 0; i < 2; ++i)
#pragma unroll
      for (int jl = 0; jl < 4; ++jl) {
        int j = t * 4 + jl;
        int kvl2 = (jl * 16 + lr) * 2;
#pragma unroll
        for (int hp = 0; hp < 2; ++hp) {
          unsigned d = pb[i][j][hp];
          int qa = i * 16 + lhi * 4 + hp * 2;
          int qb = qa + 1;
          *(unsigned short*)(sP + qa * 128 + (kvl2 ^ ((qa & 7) << 4))) =
              (unsigned short)(d & 0xffff);
          *(unsigned short*)(sP + qb * 128 + (kvl2 ^ ((qb & 7) << 4))) =
              (unsigned short)(d >> 16);
        }
      }
    // (b) attn_out float4 stores from sP — line-covering pattern
    {
      const float* ab = attn_out + (size_t)bh * 1048576 + (size_t)q0 * 1024 +
                        wid * 128 + t * 64;
#pragma unroll
      for (int s = 0; s < 8; ++s) {
        int row_l = s * 4 + (lane >> 4);
        int kvb = (lane & 15) * 8;
        bf16x4 p = *(const bf16x4*)(sP + row_l * 128 + (kvb ^ ((row_l & 7) << 4)));
        float4 o;
        o.x = bf2f((unsigned short)p[0]);
        o.y = bf2f((unsigned short)p[1]);
        o.z = bf2f((unsigned short)p[2]);
        o.w = bf2f((unsigned short)p[3]);
        *(float4*)((float*)ab + (size_t)row_l * 1024 + (lane & 15) * 4) = o;
      }
    }
    // (c) PV MFMAs: V fragments direct from global VT
#pragma unroll
    for (int c = 0; c < 2; ++c) {
      bf16x8 pf[2];
#pragma unroll
      for (int qt = 0; qt < 2; ++qt) {
        int q_ = qt * 16 + lr;
        pf[qt] = *(const bf16x8*)(sP + q_ * 128 + ((c * 64 + lhi * 16) ^ ((q_ & 7) << 4)));
      }
#pragma unroll
      for (int dt = 0; dt < 4; ++dt) {
        int d_ = dt * 16 + lr;
        bf16x8 vf = *(const bf16x8*)&VT[hb + ((size_t)d_ << 10) +
                                        wid * 128 + t * 64 + c * 32 + lhi * 8];
        oaccT[dt][0] = MFMA16(vf, pf[0], oaccT[dt][0]);
        oaccT[dt][1] = MFMA16(vf, pf[1], oaccT[dt][1]);
      }
    }
  }

  // ---- cross-wave reduce of ao partials (sAO [8][32][33], overlays sP) ----
  __syncthreads();
  float* sAO = (float*)smem;
#pragma unroll
  for (int dt = 0; dt < 4; ++dt)
#pragma unroll
    for (int qt = 0; qt < 2; ++qt)
#pragma unroll
      for (int r = 0; r < 4; ++r) {
        int q_ = qt * 16 + lr;
        int d_ = dt * 16 + lhi * 4 + r;
        sAO[wid * 1056 + q_ * 33 + d_] = oaccT[dt][qt][r];
      }
  __syncthreads();
  {
    int q_ = tid >> 4;            // 0..31
    int d0 = (tid & 15) * 4;      // 0..60
    bf16x4 o;
#pragma unroll
    for (int e = 0; e < 4; ++e) {
      int d_ = d0 + e;
      float s = 0.f;
#pragma unroll
      for (int k = 0; k < 8; ++k) s += sAO[k * 1056 + q_ * 33 + d_];
      o[e] = (short)f2bf(s);
    }
    *(bf16x4*)&ao[(size_t)(b * 1024 + q0 + q_) * 1024 + hcol + d0] = o;
  }
}

// ---------------- launch ----------------
extern "C" void kernel_launch(void* const* d_in, const int* in_sizes, int n_in,
                              void* d_out, int out_size, void* d_ws, size_t ws_size,
                              hipStream_t stream) {
  (void)in_sizes; (void)n_in; (void)out_size; (void)ws_size;
  const float* x     = (const float*)d_in[0];
  const float* ln1g  = (const float*)d_in[1];
  const float* ln1b  = (const float*)d_in[2];
  const float* qkvw  = (const float*)d_in[3];
  const float* projw = (const float*)d_in[4];
  const float* projb = (const float*)d_in[5];
  const float* g1    = (const float*)d_in[6];
  const float* ln2g  = (const float*)d_in[7];
  const float* ln2b  = (const float*)d_in[8];
  const float* fc1w  = (const float*)d_in[9];
  const float* fc1b  = (const float*)d_in[10];
  const float* fc2w  = (const float*)d_in[11];
  const float* fc2b  = (const float*)d_in[12];
  const float* g2    = (const float*)d_in[13];

  char* ws = (char*)d_ws;
  unsigned short* w_qkv  = (unsigned short*)(ws);              // 6 MB
  unsigned short* w_proj = (unsigned short*)(ws + 6291456);    // 2 MB
  unsigned short* w_fc1  = (unsigned short*)(ws + 8388608);    // 8 MB
  unsigned short* w_fc2  = (unsigned short*)(ws + 16777216);   // 8 MB
  unsigned short* n12    = (unsigned short*)(ws + 25165824);   // 8 MB (n1, later n2)
  unsigned short* Qc     = (unsigned short*)(ws + 33554432);   // 8 MB [bh][kv][d]
  unsigned short* Kc     = (unsigned short*)(ws + 41943040);   // 8 MB [bh][kv][d]
  unsigned short* VT     = (unsigned short*)(ws + 50331648);   // 8 MB [bh][d][kv]
  unsigned short* hbuf   = (unsigned short*)(ws + 33554432);   // 32 MB, overlays Qc..aob
  unsigned short* aob    = (unsigned short*)(ws + 58720256);   // 8 MB
  float*          x1     = (float*)(ws + 67108864);            // 16 MB

  float* outx = (float*)d_out;
  float* outattn = outx + (size_t)4096 * 1024;

  k_cvt4<<<12288, 256, 0, stream>>>(qkvw, projw, fc1w, fc2w,
                                    w_qkv, w_proj, w_fc1, w_fc2);

  k_ln<<<4096, 256, 0, stream>>>(x, ln1g, ln1b, n12);
  // qkv: M=4096 N=3072 K=1024 -> 192 blocks of 256^2, de-interleaved epilogue
  k_gemm256<0><<<192, 512, 0, stream>>>(n12, w_qkv, 3072, 1024, 16,
                                        nullptr, Qc, Kc, VT, nullptr);
  k_attn<<<2048, 512, 0, stream>>>(Qc, Kc, VT, outattn, aob);
  // proj: M=4096 N=1024 K=1024 -> 256 blocks of pipelined 128^2
  k_gemm128p<<<256, 256, 0, stream>>>(aob, w_proj, 1024, 1024, 32,
                                      projb, g1, x, x1);
  k_ln<<<4096, 256, 0, stream>>>(x1, ln2g, ln2b, n12);
  // fc1: M=4096 N=4096 K=1024 -> 256 blocks of 256^2
  k_gemm256<1><<<256, 512, 0, stream>>>(n12, w_fc1, 4096, 1024, 16,
                                        fc1b, nullptr, nullptr, nullptr, hbuf);
  // fc2: M=4096 N=1024 K=4096 -> 256 blocks of pipelined 128^2
  k_gemm128p<<<256, 256, 0, stream>>>(hbuf, w_fc2, 1024, 4096, 32,
                                      fc2b, g2, x1, outx);
}

// Round 15
// 312.172 us; speedup vs baseline: 1.6455x; 1.0746x over previous
//
#include <hip/hip_runtime.h>
#include <math.h>

// ---------------- types / helpers ----------------
typedef __attribute__((ext_vector_type(8))) short bf16x8;
typedef __attribute__((ext_vector_type(4))) short bf16x4;
typedef __attribute__((ext_vector_type(4))) float f32x4;

__device__ __forceinline__ unsigned short f2bf(float f) {
  unsigned u = __builtin_bit_cast(unsigned, f);
  u += 0x7fffu + ((u >> 16) & 1u);           // RNE
  return (unsigned short)(u >> 16);
}
__device__ __forceinline__ float bf2f(unsigned short h) {
  return __builtin_bit_cast(float, (unsigned)h << 16);
}

#define MFMA16(a, b, c) __builtin_amdgcn_mfma_f32_16x16x32_bf16((a), (b), (c), 0, 0, 0)

__device__ __forceinline__ void gload_lds16(const void* g, void* l) {
  __builtin_amdgcn_global_load_lds(
      (const __attribute__((address_space(1))) unsigned*)g,
      (__attribute__((address_space(3))) unsigned*)l, 16, 0, 0);
}

// bijective XCD swizzle (m204)
__device__ __forceinline__ int xcd_swz(int bid, int nwg) {
  int q = nwg >> 3, r = nwg & 7;
  int xcd = bid & 7, off = bid >> 3;
  return (xcd < r ? xcd * (q + 1) : r * (q + 1) + (xcd - r) * q) + off;
}

// ---------------- fused fp32 -> bf16 convert (all 4 weights) ----------------
__global__ __launch_bounds__(256) void k_cvt4(
    const float* __restrict__ wq, const float* __restrict__ wp,
    const float* __restrict__ w1, const float* __restrict__ w2,
    unsigned short* __restrict__ oq, unsigned short* __restrict__ op,
    unsigned short* __restrict__ o1, unsigned short* __restrict__ o2) {
  int bid = blockIdx.x;
  const float* src; unsigned short* dst; int base;
  if (bid < 3072)      { src = wq; dst = oq; base = bid; }
  else if (bid < 4096) { src = wp; dst = op; base = bid - 3072; }
  else if (bid < 8192) { src = w1; dst = o1; base = bid - 4096; }
  else                 { src = w2; dst = o2; base = bid - 8192; }
  int i = base * 256 + threadIdx.x;
  float4 v = ((const float4*)src)[i];
  bf16x4 o;
  o[0] = (short)f2bf(v.x); o[1] = (short)f2bf(v.y);
  o[2] = (short)f2bf(v.z); o[3] = (short)f2bf(v.w);
  *(bf16x4*)(dst + (size_t)i * 4) = o;
}

// ---------------- layernorm (1024 cols, 1 block/row) -> bf16 ----------------
__global__ __launch_bounds__(256) void k_ln(const float* __restrict__ x,
                                            const float* __restrict__ g,
                                            const float* __restrict__ b,
                                            unsigned short* __restrict__ out) {
  __shared__ float red[8];
  const int tid = threadIdx.x;
  const size_t row = blockIdx.x;
  float4 v = ((const float4*)(x + row * 1024))[tid];
  float s = v.x + v.y + v.z + v.w;
#pragma unroll
  for (int off = 32; off; off >>= 1) s += __shfl_xor(s, off);
  if ((tid & 63) == 0) red[tid >> 6] = s;
  __syncthreads();
  float mu = (red[0] + red[1] + red[2] + red[3]) * (1.0f / 1024.0f);
  float dx = v.x - mu, dy = v.y - mu, dz = v.z - mu, dw = v.w - mu;
  float s2 = dx * dx + dy * dy + dz * dz + dw * dw;
#pragma unroll
  for (int off = 32; off; off >>= 1) s2 += __shfl_xor(s2, off);
  if ((tid & 63) == 0) red[4 + (tid >> 6)] = s2;
  __syncthreads();
  float var = (red[4] + red[5] + red[6] + red[7]) * (1.0f / 1024.0f);
  float rstd = rsqrtf(var + 1e-5f);
  float4 gv = ((const float4*)g)[tid];
  float4 bv = ((const float4*)b)[tid];
  bf16x4 o;
  o[0] = (short)f2bf(dx * rstd * gv.x + bv.x);
  o[1] = (short)f2bf(dy * rstd * gv.y + bv.y);
  o[2] = (short)f2bf(dz * rstd * gv.z + bv.z);
  o[3] = (short)f2bf(dw * rstd * gv.w + bv.w);
  *(bf16x4*)(out + row * 1024 + tid * 4) = o;
}

// ============ 256x256 multi-phase GEMM (R9-exact): C = A @ B^T ============
template <int EPI>
__global__ __launch_bounds__(512, 2) void k_gemm256(
    const unsigned short* __restrict__ A, const unsigned short* __restrict__ Bw,
    int Ndim, int K, int nby,
    const float* __restrict__ bias,
    unsigned short* __restrict__ Qc, unsigned short* __restrict__ Kc,
    unsigned short* __restrict__ VTo,
    unsigned short* __restrict__ outb) {
  __shared__ __align__(16) unsigned short lds[2][2][16384];  // [buf][A|B][256*64]

  const int tid = threadIdx.x;
  const int wid = tid >> 6, lane = tid & 63;
  const int wm = wid >> 2, wn = wid & 3;
  const int lr = lane & 15, lhi = lane >> 4;

  const int nwg = gridDim.x;
  const int swz = xcd_swz(blockIdx.x, nwg);
  const int bcol = swz / nby, brow = swz % nby;

  const size_t a_base = (size_t)brow * 256 * K;
  const size_t b_base = (size_t)bcol * 256 * K;
  const int NT = K >> 6;

  auto STAGE = [&](int dbuf, int kt, int which) {
    int ktc = (kt < NT) ? kt : 0;
    int isB = which & 1;
    int odd = which >> 1;
    const unsigned short* src = isB ? (Bw + b_base) : (A + a_base);
    int col = (ktc << 6) + (((lane & 7) ^ ((lane >> 3) & 7)) << 3);
#pragma unroll
    for (int c = 0; c < 2; ++c) {
      int idx = (wid << 1) | c;
      int chunk = isB ? ((idx & 3) + ((idx >> 2) << 3) + (odd << 2))
                      : ((idx & 7) + ((idx >> 3) << 4) + (odd << 3));
      int row = (chunk << 3) + (lane >> 3);
      gload_lds16(src + (size_t)row * K + col,
                  &lds[dbuf][isB][chunk * 512 + lane * 8]);
    }
  };

  STAGE(0, 0, 0); STAGE(0, 0, 1); STAGE(0, 0, 2); STAGE(0, 0, 3);

  f32x4 acc[8][4] = {};
  bf16x8 aF0[4][2], aF1[4][2], bF0[2][2], bF1[2][2];

  const int colx0 = (lhi << 4) ^ ((lr & 7) << 4);
  const int colx1 = (64 + (lhi << 4)) ^ ((lr & 7) << 4);

  for (int t = 0; t < NT; ++t) {
    const int buf = t & 1;
    const char* sAb = (const char*)&lds[buf][0][0];
    const char* sBb = (const char*)&lds[buf][1][0];
#pragma unroll
    for (int q = 0; q < 4; ++q) {
      asm volatile("s_waitcnt vmcnt(6)" ::: "memory");
      __builtin_amdgcn_s_barrier();
      if (q == 0) {
#pragma unroll
        for (int m = 0; m < 4; ++m) {
          int ro = (wm * 128 + m * 16 + lr) * 128;
          aF0[m][0] = *(const bf16x8*)(sAb + ro + colx0);
          aF0[m][1] = *(const bf16x8*)(sAb + ro + colx1);
        }
      } else if (q == 1) {
#pragma unroll
        for (int n = 0; n < 2; ++n) {
          int ro = (wn * 64 + n * 16 + lr) * 128;
          bF0[n][0] = *(const bf16x8*)(sBb + ro + colx0);
          bF0[n][1] = *(const bf16x8*)(sBb + ro + colx1);
        }
      } else if (q == 2) {
#pragma unroll
        for (int m = 0; m < 4; ++m) {
          int ro = (wm * 128 + 64 + m * 16 + lr) * 128;
          aF1[m][0] = *(const bf16x8*)(sAb + ro + colx0);
          aF1[m][1] = *(const bf16x8*)(sAb + ro + colx1);
        }
      } else {
#pragma unroll
        for (int n = 0; n < 2; ++n) {
          int ro = (wn * 64 + 32 + n * 16 + lr) * 128;
          bF1[n][0] = *(const bf16x8*)(sBb + ro + colx0);
          bF1[n][1] = *(const bf16x8*)(sBb + ro + colx1);
        }
      }
      STAGE(buf ^ 1, t + 1, q);
      asm volatile("s_waitcnt lgkmcnt(0)" ::: "memory");
      __builtin_amdgcn_sched_barrier(0);
      __builtin_amdgcn_s_setprio(1);
      if (q == 0) {
        if (t > 0) {
#pragma unroll
          for (int m = 0; m < 4; ++m)
#pragma unroll
            for (int n = 0; n < 2; ++n)
#pragma unroll
              for (int kk = 0; kk < 2; ++kk)
                acc[4 + m][2 + n] = MFMA16(aF1[m][kk], bF1[n][kk], acc[4 + m][2 + n]);
        }
      } else if (q == 1) {
#pragma unroll
        for (int m = 0; m < 4; ++m)
#pragma unroll
          for (int n = 0; n < 2; ++n)
#pragma unroll
            for (int kk = 0; kk < 2; ++kk)
              acc[m][n] = MFMA16(aF0[m][kk], bF0[n][kk], acc[m][n]);
      } else if (q == 2) {
#pragma unroll
        for (int m = 0; m < 4; ++m)
#pragma unroll
          for (int n = 0; n < 2; ++n)
#pragma unroll
            for (int kk = 0; kk < 2; ++kk)
              acc[4 + m][n] = MFMA16(aF1[m][kk], bF0[n][kk], acc[4 + m][n]);
      } else {
#pragma unroll
        for (int m = 0; m < 4; ++m)
#pragma unroll
          for (int n = 0; n < 2; ++n)
#pragma unroll
            for (int kk = 0; kk < 2; ++kk)
              acc[m][2 + n] = MFMA16(aF0[m][kk], bF1[n][kk], acc[m][2 + n]);
      }
      __builtin_amdgcn_s_setprio(0);
    }
  }
#pragma unroll
  for (int m = 0; m < 4; ++m)
#pragma unroll
    for (int n = 0; n < 2; ++n)
#pragma unroll
      for (int kk = 0; kk < 2; ++kk)
        acc[4 + m][2 + n] = MFMA16(aF1[m][kk], bF1[n][kk], acc[4 + m][2 + n]);

  // ---- epilogue ----
  if (EPI == 0) {
    const int region = bcol >> 2;          // 0=Q, 1=K, 2=V (uniform)
    const int h = (bcol & 3) * 4 + wn;
    if (region < 2) {
      unsigned short* dst = (region == 0) ? Qc : Kc;  // [bh][kv][d]
#pragma unroll
      for (int m = 0; m < 8; ++m)
#pragma unroll
        for (int n = 0; n < 4; ++n) {
          int d = n * 16 + lr;
#pragma unroll
          for (int r = 0; r < 4; ++r) {
            int row = brow * 256 + wm * 128 + m * 16 + lhi * 4 + r;
            int b = row >> 10, kv = row & 1023;
            dst[((size_t)((b << 4) + h) << 16) + (size_t)kv * 64 + d] =
                f2bf(acc[m][n][r]);
          }
        }
    } else {
#pragma unroll
      for (int m = 0; m < 8; ++m)
#pragma unroll
        for (int n = 0; n < 4; ++n) {
          int d = n * 16 + lr;
          int row0_ = brow * 256 + wm * 128 + m * 16 + lhi * 4;
          int b = row0_ >> 10, kv0 = row0_ & 1023;
          bf16x4 o;
          o[0] = (short)f2bf(acc[m][n][0]);
          o[1] = (short)f2bf(acc[m][n][1]);
          o[2] = (short)f2bf(acc[m][n][2]);
          o[3] = (short)f2bf(acc[m][n][3]);
          *(bf16x4*)&VTo[((size_t)((b << 4) + h) << 16) + ((size_t)d << 10) + kv0] = o;
        }
    }
  } else {
#pragma unroll
    for (int m = 0; m < 8; ++m)
#pragma unroll
      for (int n = 0; n < 4; ++n) {
        int col = bcol * 256 + wn * 64 + n * 16 + lr;
        float bi = bias[col];
#pragma unroll
        for (int r = 0; r < 4; ++r) {
          int row = brow * 256 + wm * 128 + m * 16 + lhi * 4 + r;
          float v = acc[m][n][r] + bi;
          v = 0.5f * v * (1.0f + erff(v * 0.70710678118654752f));
          outb[(size_t)row * Ndim + col] = f2bf(v);
        }
      }
  }
}

// ======== 128x128 PIPELINED GEMM (4-phase counted-vmcnt) — R9-exact ========
__global__ __launch_bounds__(256) void k_gemm128p(
    const unsigned short* __restrict__ A, const unsigned short* __restrict__ Bw,
    int Ndim, int K, int nby,
    const float* __restrict__ bias, const float* __restrict__ gamma,
    const float* __restrict__ resid, float* __restrict__ outf) {
  __shared__ __align__(16) unsigned short lds[2][2][8192];  // [buf][A|B][128*64]

  const int tid = threadIdx.x;
  const int wid = tid >> 6, lane = tid & 63;
  const int wm = wid >> 1, wn = wid & 1;
  const int lr = lane & 15, lhi = lane >> 4;

  const int swz = xcd_swz(blockIdx.x, gridDim.x);
  const int bcol = swz / nby, brow = swz % nby;

  const size_t a_base = (size_t)brow * 128 * K;
  const size_t b_base = (size_t)bcol * 128 * K;
  const int NT = K >> 6;

  auto STAGE = [&](int dbuf, int kt, int which) {
    int ktc = (kt < NT) ? kt : 0;
    int isB = which & 1;
    int odd = which >> 1;
    const unsigned short* src = isB ? (Bw + b_base) : (A + a_base);
    int col = (ktc << 6) + (((lane & 7) ^ ((lane >> 3) & 7)) << 3);
#pragma unroll
    for (int c = 0; c < 2; ++c) {
      int idx = (wid << 1) | c;                            // 0..7
      int chunk = (idx & 3) + ((idx >> 2) << 3) + (odd << 2);
      int row = (chunk << 3) + (lane >> 3);
      gload_lds16(src + (size_t)row * K + col,
                  &lds[dbuf][isB][chunk * 512 + lane * 8]);
    }
  };

  STAGE(0, 0, 0); STAGE(0, 0, 1); STAGE(0, 0, 2); STAGE(0, 0, 3);

  f32x4 acc[4][4] = {};
  bf16x8 aF0[2][2], aF1[2][2], bF0[2][2], bF1[2][2];

  const int colx0 = (lhi << 4) ^ ((lr & 7) << 4);
  const int colx1 = (64 + (lhi << 4)) ^ ((lr & 7) << 4);

  for (int t = 0; t < NT; ++t) {
    const int buf = t & 1;
    const char* sAb = (const char*)&lds[buf][0][0];
    const char* sBb = (const char*)&lds[buf][1][0];
#pragma unroll
    for (int q = 0; q < 4; ++q) {
      asm volatile("s_waitcnt vmcnt(6)" ::: "memory");
      __builtin_amdgcn_s_barrier();
      if (q == 0) {
#pragma unroll
        for (int m = 0; m < 2; ++m) {
          int ro = (wm * 64 + m * 16 + lr) * 128;
          aF0[m][0] = *(const bf16x8*)(sAb + ro + colx0);
          aF0[m][1] = *(const bf16x8*)(sAb + ro + colx1);
        }
      } else if (q == 1) {
#pragma unroll
        for (int n = 0; n < 2; ++n) {
          int ro = (wn * 64 + n * 16 + lr) * 128;
          bF0[n][0] = *(const bf16x8*)(sBb + ro + colx0);
          bF0[n][1] = *(const bf16x8*)(sBb + ro + colx1);
        }
      } else if (q == 2) {
#pragma unroll
        for (int m = 0; m < 2; ++m) {
          int ro = (wm * 64 + 32 + m * 16 + lr) * 128;
          aF1[m][0] = *(const bf16x8*)(sAb + ro + colx0);
          aF1[m][1] = *(const bf16x8*)(sAb + ro + colx1);
        }
      } else {
#pragma unroll
        for (int n = 0; n < 2; ++n) {
          int ro = (wn * 64 + 32 + n * 16 + lr) * 128;
          bF1[n][0] = *(const bf16x8*)(sBb + ro + colx0);
          bF1[n][1] = *(const bf16x8*)(sBb + ro + colx1);
        }
      }
      STAGE(buf ^ 1, t + 1, q);
      asm volatile("s_waitcnt lgkmcnt(0)" ::: "memory");
      __builtin_amdgcn_sched_barrier(0);
      __builtin_amdgcn_s_setprio(1);
      if (q == 0) {
        if (t > 0) {
#pragma unroll
          for (int m = 0; m < 2; ++m)
#pragma unroll
            for (int n = 0; n < 2; ++n)
#pragma unroll
              for (int kk = 0; kk < 2; ++kk)
                acc[2 + m][2 + n] = MFMA16(aF1[m][kk], bF1[n][kk], acc[2 + m][2 + n]);
        }
      } else if (q == 1) {
#pragma unroll
        for (int m = 0; m < 2; ++m)
#pragma unroll
          for (int n = 0; n < 2; ++n)
#pragma unroll
            for (int kk = 0; kk < 2; ++kk)
              acc[m][n] = MFMA16(aF0[m][kk], bF0[n][kk], acc[m][n]);
      } else if (q == 2) {
#pragma unroll
        for (int m = 0; m < 2; ++m)
#pragma unroll
          for (int n = 0; n < 2; ++n)
#pragma unroll
            for (int kk = 0; kk < 2; ++kk)
              acc[2 + m][n] = MFMA16(aF1[m][kk], bF0[n][kk], acc[2 + m][n]);
      } else {
#pragma unroll
        for (int m = 0; m < 2; ++m)
#pragma unroll
          for (int n = 0; n < 2; ++n)
#pragma unroll
            for (int kk = 0; kk < 2; ++kk)
              acc[m][2 + n] = MFMA16(aF0[m][kk], bF1[n][kk], acc[m][2 + n]);
      }
      __builtin_amdgcn_s_setprio(0);
    }
  }
#pragma unroll
  for (int m = 0; m < 2; ++m)
#pragma unroll
    for (int n = 0; n < 2; ++n)
#pragma unroll
      for (int kk = 0; kk < 2; ++kk)
        acc[2 + m][2 + n] = MFMA16(aF1[m][kk], bF1[n][kk], acc[2 + m][2 + n]);

  // ---- epilogue: resid + (v + bias)*gamma -> f32 ----
#pragma unroll
  for (int i = 0; i < 4; ++i)
#pragma unroll
    for (int j = 0; j < 4; ++j) {
      int col = bcol * 128 + wn * 64 + (j >> 1) * 32 + (j & 1) * 16 + lr;
      float bi = bias[col], gm = gamma[col];
#pragma unroll
      for (int r = 0; r < 4; ++r) {
        int row = brow * 128 + wm * 64 + (i >> 1) * 32 + (i & 1) * 16 + lhi * 4 + r;
        outf[(size_t)row * Ndim + col] =
            resid[(size_t)row * Ndim + col] + (acc[i][j][r] + bi) * gm;
      }
    }
}

// ---------------- fused attention v10: R9-exact v7 + NONTEMPORAL attn stores ----------------
// The only change vs R9: section (b) stores use __builtin_nontemporal_store with an
// ext_vector f32x4 (HIP float4 is rejected by the builtin) — MUBUF nt, bypass L2.
__global__ __launch_bounds__(256) void k_attn(const unsigned short* __restrict__ Qc,
                                              const unsigned short* __restrict__ Kc,
                                              const unsigned short* __restrict__ VT,
                                              float* __restrict__ attn_out,
                                              unsigned short* __restrict__ ao) {
  __shared__ __align__(16) char smem[16896];  // sP 4x4096; sAO overlays
  __shared__ float red[4][32][2];             // [wave][q-row][m,l]

  const int tid = threadIdx.x;
  const int wid = tid >> 6, lane = tid & 63;
  const int lr = lane & 15, lhi = lane >> 4;
  const int bid = blockIdx.x;
  const int bh = (bid & 7) + ((bid >> 8) << 3);   // XCD affinity: head -> one XCD
  const int q0 = ((bid >> 3) & 31) * 32;
  const int b = bh >> 4, h = bh & 15;
  const size_t hb = (size_t)bh << 16;  // per-head base (1024*64 elems)
  const int hcol = h * 64;

  bf16x8 af[2][2];
#pragma unroll
  for (int i = 0; i < 2; ++i)
#pragma unroll
    for (int kk = 0; kk < 2; ++kk)
      af[i][kk] = *(const bf16x8*)&Qc[hb + (size_t)(q0 + i * 16 + lr) * 64 +
                                      kk * 32 + lhi * 8];

  f32x4 acc[2][16] = {};
#pragma unroll
  for (int kk = 0; kk < 2; ++kk) {
#pragma unroll
    for (int j = 0; j < 16; ++j) {
      int m = wid * 256 + j * 16 + lr;
      bf16x8 bv = *(const bf16x8*)&Kc[hb + (size_t)m * 64 + kk * 32 + lhi * 8];
      acc[0][j] = MFMA16(af[0][kk], bv, acc[0][j]);
      acc[1][j] = MFMA16(af[1][kk], bv, acc[1][j]);
    }
  }

  float mw[2][4];
#pragma unroll
  for (int i = 0; i < 2; ++i)
#pragma unroll
    for (int r = 0; r < 4; ++r) {
      float m_ = -1e30f;
#pragma unroll
      for (int j = 0; j < 16; ++j) {
        acc[i][j][r] *= 0.125f;
        m_ = fmaxf(m_, acc[i][j][r]);
      }
#pragma unroll
      for (int off = 1; off < 16; off <<= 1) m_ = fmaxf(m_, __shfl_xor(m_, off));
      mw[i][r] = m_;
      float s_ = 0.f;
#pragma unroll
      for (int j = 0; j < 16; ++j) {
        float e = __expf(acc[i][j][r] - m_);
        acc[i][j][r] = e;
        s_ += e;
      }
#pragma unroll
      for (int off = 1; off < 16; off <<= 1) s_ += __shfl_xor(s_, off);
      if (lr == 0) {
        int rl = i * 16 + lhi * 4 + r;
        red[wid][rl][0] = m_;
        red[wid][rl][1] = s_;
      }
    }
  __syncthreads();

  float inv[2][4];
#pragma unroll
  for (int i = 0; i < 2; ++i)
#pragma unroll
    for (int r = 0; r < 4; ++r) {
      int rl = i * 16 + lhi * 4 + r;
      float m0 = red[0][rl][0], m1 = red[1][rl][0],
            m2 = red[2][rl][0], m3 = red[3][rl][0];
      float mg = fmaxf(fmaxf(m0, m1), fmaxf(m2, m3));
      float lg = red[0][rl][1] * __expf(m0 - mg) + red[1][rl][1] * __expf(m1 - mg) +
                 red[2][rl][1] * __expf(m2 - mg) + red[3][rl][1] * __expf(m3 - mg);
      inv[i][r] = __expf(mw[i][r] - mg) / lg;
    }

  unsigned pb[2][16][2];
#pragma unroll
  for (int i = 0; i < 2; ++i)
#pragma unroll
    for (int j = 0; j < 16; ++j) {
      pb[i][j][0] = (unsigned)f2bf(acc[i][j][0] * inv[i][0]) |
                    ((unsigned)f2bf(acc[i][j][1] * inv[i][1]) << 16);
      pb[i][j][1] = (unsigned)f2bf(acc[i][j][2] * inv[i][2]) |
                    ((unsigned)f2bf(acc[i][j][3] * inv[i][3]) << 16);
    }

  char* sP = smem + wid * 4096;
  f32x4 oaccT[4][2] = {};

#pragma unroll
  for (int t = 0; t < 4; ++t) {
#pragma unroll
    for (int i = 0; i < 2; ++i)
#pragma unroll
      for (int jl = 0; jl < 4; ++jl) {
        int j = t * 4 + jl;
        int kvl2 = (jl * 16 + lr) * 2;
#pragma unroll
        for (int hp = 0; hp < 2; ++hp) {
          unsigned d = pb[i][j][hp];
          int qa = i * 16 + lhi * 4 + hp * 2;
          int qb = qa + 1;
          *(unsigned short*)(sP + qa * 128 + (kvl2 ^ ((qa & 7) << 4))) =
              (unsigned short)(d & 0xffff);
          *(unsigned short*)(sP + qb * 128 + (kvl2 ^ ((qb & 7) << 4))) =
              (unsigned short)(d >> 16);
        }
      }
    // (b) attn_out stores — NONTEMPORAL via ext_vector f32x4 (bypass L2)
    {
      float* ab = attn_out + (size_t)bh * 1048576 + (size_t)q0 * 1024 +
                  wid * 256 + t * 64;
#pragma unroll
      for (int s = 0; s < 8; ++s) {
        int row_l = s * 4 + (lane >> 4);
        int kvb = (lane & 15) * 8;
        bf16x4 p = *(const bf16x4*)(sP + row_l * 128 + (kvb ^ ((row_l & 7) << 4)));
        f32x4 o;
        o[0] = bf2f((unsigned short)p[0]);
        o[1] = bf2f((unsigned short)p[1]);
        o[2] = bf2f((unsigned short)p[2]);
        o[3] = bf2f((unsigned short)p[3]);
        __builtin_nontemporal_store(o, (f32x4*)(ab + (size_t)row_l * 1024 +
                                                (lane & 15) * 4));
      }
    }
#pragma unroll
    for (int c = 0; c < 2; ++c) {
      bf16x8 pf[2];
#pragma unroll
      for (int qt = 0; qt < 2; ++qt) {
        int q_ = qt * 16 + lr;
        pf[qt] = *(const bf16x8*)(sP + q_ * 128 + ((c * 64 + lhi * 16) ^ ((q_ & 7) << 4)));
      }
#pragma unroll
      for (int dt = 0; dt < 4; ++dt) {
        int d_ = dt * 16 + lr;
        bf16x8 vf = *(const bf16x8*)&VT[hb + ((size_t)d_ << 10) +
                                        wid * 256 + t * 64 + c * 32 + lhi * 8];
        oaccT[dt][0] = MFMA16(vf, pf[0], oaccT[dt][0]);
        oaccT[dt][1] = MFMA16(vf, pf[1], oaccT[dt][1]);
      }
    }
  }

  __syncthreads();
  float* sAO = (float*)smem;
#pragma unroll
  for (int dt = 0; dt < 4; ++dt)
#pragma unroll
    for (int qt = 0; qt < 2; ++qt)
#pragma unroll
      for (int r = 0; r < 4; ++r) {
        int q_ = qt * 16 + lr;
        int d_ = dt * 16 + lhi * 4 + r;
        sAO[wid * 1056 + q_ * 33 + d_] = oaccT[dt][qt][r];
      }
  __syncthreads();
  {
    int q_ = tid >> 3;
    int d0 = (tid & 7) * 8;
    bf16x8 o;
#pragma unroll
    for (int e = 0; e < 8; ++e) {
      int d_ = d0 + e;
      float s = sAO[q_ * 33 + d_] + sAO[1056 + q_ * 33 + d_] +
                sAO[2112 + q_ * 33 + d_] + sAO[3168 + q_ * 33 + d_];
      o[e] = (short)f2bf(s);
    }
    *(bf16x8*)&ao[(size_t)(b * 1024 + q0 + q_) * 1024 + hcol + d0] = o;
  }
}

// ---------------- launch ----------------
extern "C" void kernel_launch(void* const* d_in, const int* in_sizes, int n_in,
                              void* d_out, int out_size, void* d_ws, size_t ws_size,
                              hipStream_t stream) {
  (void)in_sizes; (void)n_in; (void)out_size; (void)ws_size;
  const float* x     = (const float*)d_in[0];
  const float* ln1g  = (const float*)d_in[1];
  const float* ln1b  = (const float*)d_in[2];
  const float* qkvw  = (const float*)d_in[3];
  const float* projw = (const float*)d_in[4];
  const float* projb = (const float*)d_in[5];
  const float* g1    = (const float*)d_in[6];
  const float* ln2g  = (const float*)d_in[7];
  const float* ln2b  = (const float*)d_in[8];
  const float* fc1w  = (const float*)d_in[9];
  const float* fc1b  = (const float*)d_in[10];
  const float* fc2w  = (const float*)d_in[11];
  const float* fc2b  = (const float*)d_in[12];
  const float* g2    = (const float*)d_in[13];

  char* ws = (char*)d_ws;
  unsigned short* w_qkv  = (unsigned short*)(ws);              // 6 MB
  unsigned short* w_proj = (unsigned short*)(ws + 6291456);    // 2 MB
  unsigned short* w_fc1  = (unsigned short*)(ws + 8388608);    // 8 MB
  unsigned short* w_fc2  = (unsigned short*)(ws + 16777216);   // 8 MB
  unsigned short* n12    = (unsigned short*)(ws + 25165824);   // 8 MB (n1, later n2)
  unsigned short* Qc     = (unsigned short*)(ws + 33554432);   // 8 MB [bh][kv][d]
  unsigned short* Kc     = (unsigned short*)(ws + 41943040);   // 8 MB [bh][kv][d]
  unsigned short* VT     = (unsigned short*)(ws + 50331648);   // 8 MB [bh][d][kv]
  unsigned short* hbuf   = (unsigned short*)(ws + 33554432);   // 32 MB, overlays Qc..aob
  unsigned short* aob    = (unsigned short*)(ws + 58720256);   // 8 MB
  float*          x1     = (float*)(ws + 67108864);            // 16 MB

  float* outx = (float*)d_out;
  float* outattn = outx + (size_t)4096 * 1024;

  k_cvt4<<<12288, 256, 0, stream>>>(qkvw, projw, fc1w, fc2w,
                                    w_qkv, w_proj, w_fc1, w_fc2);

  k_ln<<<4096, 256, 0, stream>>>(x, ln1g, ln1b, n12);
  // qkv: M=4096 N=3072 K=1024 -> 192 blocks of 256^2, de-interleaved epilogue
  k_gemm256<0><<<192, 512, 0, stream>>>(n12, w_qkv, 3072, 1024, 16,
                                        nullptr, Qc, Kc, VT, nullptr);
  k_attn<<<2048, 256, 0, stream>>>(Qc, Kc, VT, outattn, aob);
  // proj: M=4096 N=1024 K=1024 -> 256 blocks of pipelined 128^2
  k_gemm128p<<<256, 256, 0, stream>>>(aob, w_proj, 1024, 1024, 32,
                                      projb, g1, x, x1);
  k_ln<<<4096, 256, 0, stream>>>(x1, ln2g, ln2b, n12);
  // fc1: M=4096 N=4096 K=1024 -> 256 blocks of 256^2
  k_gemm256<1><<<256, 512, 0, stream>>>(n12, w_fc1, 4096, 1024, 16,
                                        fc1b, nullptr, nullptr, nullptr, hbuf);
  // fc2: M=4096 N=1024 K=4096 -> 256 blocks of pipelined 128^2
  k_gemm128p<<<256, 256, 0, stream>>>(hbuf, w_fc2, 1024, 4096, 32,
                                      fc2b, g2, x1, outx);
}